// Round 1
// baseline (341.207 us; speedup 1.0000x reference)
//
#include <hip/hip_runtime.h>
#include <hip/hip_bf16.h>

// Problem dims (fixed)
// B=2, N=2048, D=1024, H=16, DK=64
// x: [2,2048,1024] f32; Wkqv: [16,1024,192] f32; bkqv: [16,192] f32;
// Wproj: [1024,1024] f32; bproj: [1024] f32; out: [2,2048,1024] f32

typedef __bf16 bf16x8 __attribute__((ext_vector_type(8)));
typedef float f32x4 __attribute__((ext_vector_type(4)));

#define MFMA_BF16 __builtin_amdgcn_mfma_f32_16x16x32_bf16

// ---------------- prep kernels ----------------

// f32 -> bf16, 4 elems/thread, exact coverage
__global__ __launch_bounds__(256) void cvt_f32_bf16(const float* __restrict__ in,
                                                    __hip_bfloat16* __restrict__ out) {
    int i = (blockIdx.x * 256 + threadIdx.x) * 4;
    float4 v = *(const float4*)&in[i];
    struct alignas(8) bh4 { __hip_bfloat16 a, b, c, d; };
    bh4 r{__float2bfloat16(v.x), __float2bfloat16(v.y),
          __float2bfloat16(v.z), __float2bfloat16(v.w)};
    *(bh4*)&out[i] = r;
}

// in [b][R][C] f32 -> out [b][C][R] bf16 ; 32x32 tiles, block (32,8)
__global__ __launch_bounds__(256) void transpose_cvt(const float* __restrict__ in,
                                                     __hip_bfloat16* __restrict__ out,
                                                     int R, int C) {
    __shared__ float tile[32][33];
    int b = blockIdx.z;
    int r0 = blockIdx.y * 32, c0 = blockIdx.x * 32;
    int tx = threadIdx.x, ty = threadIdx.y;
    const float* ip = in + (size_t)b * R * C;
    __hip_bfloat16* op = out + (size_t)b * R * C;
#pragma unroll
    for (int j = 0; j < 32; j += 8)
        tile[ty + j][tx] = ip[(size_t)(r0 + ty + j) * C + (c0 + tx)];
    __syncthreads();
#pragma unroll
    for (int j = 0; j < 32; j += 8)
        op[(size_t)(c0 + ty + j) * R + (r0 + tx)] = __float2bfloat16(tile[tx][ty + j]);
}

// ---------------- QKV GEMM ----------------
// C[4096][3072] = A[4096][1024] @ Bt[3072][1024]^T + bias, then de-interleave
// into K[bh][n][64], Q[bh][n][64], Vt[bh][64][2048] (all bf16).
__global__ __launch_bounds__(256) void gemm_qkv(const __hip_bfloat16* __restrict__ Ag,
                                                const __hip_bfloat16* __restrict__ Btg,
                                                const float* __restrict__ bias,
                                                __hip_bfloat16* __restrict__ Kb,
                                                __hip_bfloat16* __restrict__ Qb,
                                                __hip_bfloat16* __restrict__ Vt) {
    __shared__ __hip_bfloat16 As[64][72];
    __shared__ __hip_bfloat16 Bs[64][72];
    const int t = threadIdx.x;
    const int lane = t & 63, wid = t >> 6;
    const int wm = wid >> 1, wn = wid & 1;
    const int row0 = blockIdx.y * 64, col0 = blockIdx.x * 64;
    const int lr = lane & 15, lg = lane >> 4;
    const int sr = t >> 2, sc = (t & 3) * 16;

    f32x4 acc[2][2] = {};
    for (int k0 = 0; k0 < 1024; k0 += 64) {
        *(uint4*)&As[sr][sc]     = *(const uint4*)&Ag[(size_t)(row0 + sr) * 1024 + k0 + sc];
        *(uint4*)&As[sr][sc + 8] = *(const uint4*)&Ag[(size_t)(row0 + sr) * 1024 + k0 + sc + 8];
        *(uint4*)&Bs[sr][sc]     = *(const uint4*)&Btg[(size_t)(col0 + sr) * 1024 + k0 + sc];
        *(uint4*)&Bs[sr][sc + 8] = *(const uint4*)&Btg[(size_t)(col0 + sr) * 1024 + k0 + sc + 8];
        __syncthreads();
#pragma unroll
        for (int kk = 0; kk < 64; kk += 32) {
            bf16x8 a0 = *(const bf16x8*)&As[wm * 32 + lr][kk + 8 * lg];
            bf16x8 a1 = *(const bf16x8*)&As[wm * 32 + 16 + lr][kk + 8 * lg];
            bf16x8 b0 = *(const bf16x8*)&Bs[wn * 32 + lr][kk + 8 * lg];
            bf16x8 b1 = *(const bf16x8*)&Bs[wn * 32 + 16 + lr][kk + 8 * lg];
            acc[0][0] = MFMA_BF16(a0, b0, acc[0][0], 0, 0, 0);
            acc[0][1] = MFMA_BF16(a0, b1, acc[0][1], 0, 0, 0);
            acc[1][0] = MFMA_BF16(a1, b0, acc[1][0], 0, 0, 0);
            acc[1][1] = MFMA_BF16(a1, b1, acc[1][1], 0, 0, 0);
        }
        __syncthreads();
    }
#pragma unroll
    for (int mt = 0; mt < 2; ++mt)
#pragma unroll
        for (int nt = 0; nt < 2; ++nt)
#pragma unroll
            for (int r = 0; r < 4; ++r) {
                int rg = row0 + wm * 32 + mt * 16 + lg * 4 + r;  // bn index
                int cg = col0 + wn * 32 + nt * 16 + lr;          // h*192+e
                float v = acc[mt][nt][r] + bias[cg];
                int h = cg / 192, e = cg % 192;
                int d = e / 3, which = e % 3;
                int b = rg >> 11, n = rg & 2047;
                int bh = b * 16 + h;
                __hip_bfloat16 hv = __float2bfloat16(v);
                if (which == 0)      Kb[((size_t)bh * 2048 + n) * 64 + d] = hv;
                else if (which == 1) Qb[((size_t)bh * 2048 + n) * 64 + d] = hv;
                else                 Vt[((size_t)bh * 64 + d) * 2048 + n] = hv;
            }
}

// ---------------- flash attention ----------------
// scores[n][m] = k[n] . q[m] / 8 ; causal m <= n ; sa = softmax @ v
// grid (qb=N/64, bh=32), 4 independent waves x 16 rows each. No __syncthreads.
__global__ __launch_bounds__(256) void attn_fwd(const __hip_bfloat16* __restrict__ Kb,
                                                const __hip_bfloat16* __restrict__ Qb,
                                                const __hip_bfloat16* __restrict__ Vt,
                                                __hip_bfloat16* __restrict__ sa) {
    __shared__ __hip_bfloat16 Pl[4][16][72];  // per-wave P tile, padded
    const int qb = blockIdx.x, bh = blockIdx.y;
    const int t = threadIdx.x, lane = t & 63, wid = t >> 6;
    const int lr = lane & 15, lg = lane >> 4;
    const int n0 = qb * 64 + wid * 16;

    // A-frag rows: k[n0+lr][*], K=64 -> 2 frags
    const __hip_bfloat16* Kp = Kb + ((size_t)bh * 2048 + n0) * 64;
    bf16x8 ak0 = *(const bf16x8*)&Kp[lr * 64 + 8 * lg];
    bf16x8 ak1 = *(const bf16x8*)&Kp[lr * 64 + 32 + 8 * lg];

    f32x4 o[4] = {};
    float mrun[4] = {-1e30f, -1e30f, -1e30f, -1e30f};
    float lrun[4] = {0.f, 0.f, 0.f, 0.f};

    for (int m0 = 0; m0 <= n0 + 15; m0 += 64) {
        const __hip_bfloat16* Qp = Qb + ((size_t)bh * 2048 + m0) * 64;
        f32x4 s[4];
#pragma unroll
        for (int ct = 0; ct < 4; ++ct) {
            f32x4 z = {};
            bf16x8 bq0 = *(const bf16x8*)&Qp[(ct * 16 + lr) * 64 + 8 * lg];
            bf16x8 bq1 = *(const bf16x8*)&Qp[(ct * 16 + lr) * 64 + 32 + 8 * lg];
            z = MFMA_BF16(ak0, bq0, z, 0, 0, 0);
            z = MFMA_BF16(ak1, bq1, z, 0, 0, 0);
            s[ct] = z * 0.125f;
        }
        if (m0 + 63 > n0) {  // diagonal block: elementwise causal mask
#pragma unroll
            for (int ct = 0; ct < 4; ++ct)
#pragma unroll
                for (int r = 0; r < 4; ++r) {
                    int m = m0 + ct * 16 + lr;
                    int n = n0 + lg * 4 + r;
                    if (m > n) s[ct][r] = -1e30f;
                }
        }
        float scale_old[4];
#pragma unroll
        for (int r = 0; r < 4; ++r) {
            float mx = fmaxf(fmaxf(s[0][r], s[1][r]), fmaxf(s[2][r], s[3][r]));
#pragma unroll
            for (int off = 1; off < 16; off <<= 1) mx = fmaxf(mx, __shfl_xor(mx, off));
            float nm = fmaxf(mrun[r], mx);
            scale_old[r] = __expf(mrun[r] - nm);
            mrun[r] = nm;
#pragma unroll
            for (int ct = 0; ct < 4; ++ct) s[ct][r] = __expf(s[ct][r] - nm);
            float rs = s[0][r] + s[1][r] + s[2][r] + s[3][r];
#pragma unroll
            for (int off = 1; off < 16; off <<= 1) rs += __shfl_xor(rs, off);
            lrun[r] = lrun[r] * scale_old[r] + rs;
        }
#pragma unroll
        for (int dt = 0; dt < 4; ++dt)
#pragma unroll
            for (int r = 0; r < 4; ++r) o[dt][r] *= scale_old[r];

        // P (D-frag layout) -> LDS -> A-frag layout
#pragma unroll
        for (int ct = 0; ct < 4; ++ct)
#pragma unroll
            for (int r = 0; r < 4; ++r)
                Pl[wid][lg * 4 + r][ct * 16 + lr] = __float2bfloat16(s[ct][r]);

#pragma unroll
        for (int ks = 0; ks < 2; ++ks) {
            bf16x8 ap = *(const bf16x8*)&Pl[wid][lr][ks * 32 + 8 * lg];
#pragma unroll
            for (int dt = 0; dt < 4; ++dt) {
                bf16x8 bv = *(const bf16x8*)&Vt[((size_t)bh * 64 + dt * 16 + lr) * 2048 +
                                                m0 + ks * 32 + 8 * lg];
                o[dt] = MFMA_BF16(ap, bv, o[dt], 0, 0, 0);
            }
        }
    }

    const int b = bh >> 4, h = bh & 15;
#pragma unroll
    for (int r = 0; r < 4; ++r) {
        float inv = 1.0f / lrun[r];
        int rowg = b * 2048 + n0 + lg * 4 + r;
#pragma unroll
        for (int dt = 0; dt < 4; ++dt)
            sa[(size_t)rowg * 1024 + h * 64 + dt * 16 + lr] =
                __float2bfloat16(o[dt][r] * inv);
    }
}

// ---------------- output projection ----------------
__global__ __launch_bounds__(256) void gemm_proj(const __hip_bfloat16* __restrict__ Ag,
                                                 const __hip_bfloat16* __restrict__ Btg,
                                                 const float* __restrict__ bias,
                                                 float* __restrict__ out) {
    __shared__ __hip_bfloat16 As[64][72];
    __shared__ __hip_bfloat16 Bs[64][72];
    const int t = threadIdx.x;
    const int lane = t & 63, wid = t >> 6;
    const int wm = wid >> 1, wn = wid & 1;
    const int row0 = blockIdx.y * 64, col0 = blockIdx.x * 64;
    const int lr = lane & 15, lg = lane >> 4;
    const int sr = t >> 2, sc = (t & 3) * 16;

    f32x4 acc[2][2] = {};
    for (int k0 = 0; k0 < 1024; k0 += 64) {
        *(uint4*)&As[sr][sc]     = *(const uint4*)&Ag[(size_t)(row0 + sr) * 1024 + k0 + sc];
        *(uint4*)&As[sr][sc + 8] = *(const uint4*)&Ag[(size_t)(row0 + sr) * 1024 + k0 + sc + 8];
        *(uint4*)&Bs[sr][sc]     = *(const uint4*)&Btg[(size_t)(col0 + sr) * 1024 + k0 + sc];
        *(uint4*)&Bs[sr][sc + 8] = *(const uint4*)&Btg[(size_t)(col0 + sr) * 1024 + k0 + sc + 8];
        __syncthreads();
#pragma unroll
        for (int kk = 0; kk < 64; kk += 32) {
            bf16x8 a0 = *(const bf16x8*)&As[wm * 32 + lr][kk + 8 * lg];
            bf16x8 a1 = *(const bf16x8*)&As[wm * 32 + 16 + lr][kk + 8 * lg];
            bf16x8 b0 = *(const bf16x8*)&Bs[wn * 32 + lr][kk + 8 * lg];
            bf16x8 b1 = *(const bf16x8*)&Bs[wn * 32 + 16 + lr][kk + 8 * lg];
            acc[0][0] = MFMA_BF16(a0, b0, acc[0][0], 0, 0, 0);
            acc[0][1] = MFMA_BF16(a0, b1, acc[0][1], 0, 0, 0);
            acc[1][0] = MFMA_BF16(a1, b0, acc[1][0], 0, 0, 0);
            acc[1][1] = MFMA_BF16(a1, b1, acc[1][1], 0, 0, 0);
        }
        __syncthreads();
    }
#pragma unroll
    for (int mt = 0; mt < 2; ++mt)
#pragma unroll
        for (int nt = 0; nt < 2; ++nt)
#pragma unroll
            for (int r = 0; r < 4; ++r) {
                int rg = row0 + wm * 32 + mt * 16 + lg * 4 + r;
                int cg = col0 + wn * 32 + nt * 16 + lr;
                out[(size_t)rg * 1024 + cg] = acc[mt][nt][r] + bias[cg];
            }
}

// ---------------- launch ----------------
extern "C" void kernel_launch(void* const* d_in, const int* in_sizes, int n_in,
                              void* d_out, int out_size, void* d_ws, size_t ws_size,
                              hipStream_t stream) {
    const float* x     = (const float*)d_in[0];  // [2,2048,1024]
    const float* Wkqv  = (const float*)d_in[1];  // [16,1024,192]
    const float* bkqv  = (const float*)d_in[2];  // [16,192] -> flat [3072]
    const float* Wproj = (const float*)d_in[3];  // [1024,1024]
    const float* bproj = (const float*)d_in[4];  // [1024]

    char* w = (char*)d_ws;
    // workspace layout (bytes)
    __hip_bfloat16* xb  = (__hip_bfloat16*)(w + 0);          //  8388608
    __hip_bfloat16* Wt  = (__hip_bfloat16*)(w + 8388608);    //  6291456  [16][192][1024]
    __hip_bfloat16* WpT = (__hip_bfloat16*)(w + 14680064);   //  2097152  [1024][1024]
    __hip_bfloat16* Kb  = (__hip_bfloat16*)(w + 16777216);   //  8388608  [32][2048][64]
    __hip_bfloat16* Qb  = (__hip_bfloat16*)(w + 25165824);   //  8388608
    __hip_bfloat16* Vt  = (__hip_bfloat16*)(w + 33554432);   //  8388608  [32][64][2048]
    __hip_bfloat16* sab = (__hip_bfloat16*)(w + 41943040);   //  8388608  [4096][1024]
    if (ws_size < 50331648) return;

    cvt_f32_bf16<<<4096, 256, 0, stream>>>(x, xb);
    transpose_cvt<<<dim3(6, 32, 16), dim3(32, 8), 0, stream>>>(Wkqv, Wt, 1024, 192);
    transpose_cvt<<<dim3(32, 32, 1), dim3(32, 8), 0, stream>>>(Wproj, WpT, 1024, 1024);
    gemm_qkv<<<dim3(48, 64), 256, 0, stream>>>(xb, Wt, bkqv, Kb, Qb, Vt);
    attn_fwd<<<dim3(32, 32), 256, 0, stream>>>(Kb, Qb, Vt, sab);
    gemm_proj<<<dim3(16, 64), 256, 0, stream>>>(sab, WpT, bproj, (float*)d_out);
}

// Round 2
// 194.198 us; speedup vs baseline: 1.7570x; 1.7570x over previous
//
#include <hip/hip_runtime.h>
#include <hip/hip_bf16.h>

// Problem dims (fixed)
// B=2, N=2048, D=1024, H=16, DK=64
// x: [2,2048,1024] f32; Wkqv: [16,1024,192] f32; bkqv: [16,192] f32;
// Wproj: [1024,1024] f32; bproj: [1024] f32; out: [2,2048,1024] f32

typedef __bf16 bf16x8 __attribute__((ext_vector_type(8)));
typedef float f32x4 __attribute__((ext_vector_type(4)));
typedef float f32x16 __attribute__((ext_vector_type(16)));

#define MFMA_BF16 __builtin_amdgcn_mfma_f32_16x16x32_bf16
#define MFMA32 __builtin_amdgcn_mfma_f32_32x32x16_bf16

static __device__ __forceinline__ unsigned cvtpk(float lo, float hi) {
    unsigned r;
    asm("v_cvt_pk_bf16_f32 %0, %1, %2" : "=v"(r) : "v"(lo), "v"(hi));
    return r;
}

// ---------------- prep kernels ----------------

__global__ __launch_bounds__(256) void cvt_f32_bf16(const float* __restrict__ in,
                                                    __hip_bfloat16* __restrict__ out) {
    int i = (blockIdx.x * 256 + threadIdx.x) * 4;
    float4 v = *(const float4*)&in[i];
    struct alignas(8) bh4 { __hip_bfloat16 a, b, c, d; };
    bh4 r{__float2bfloat16(v.x), __float2bfloat16(v.y),
          __float2bfloat16(v.z), __float2bfloat16(v.w)};
    *(bh4*)&out[i] = r;
}

// in [b][R][C] f32 -> out [b][C][R] bf16 ; 32x32 tiles, block (32,8)
__global__ __launch_bounds__(256) void transpose_cvt(const float* __restrict__ in,
                                                     __hip_bfloat16* __restrict__ out,
                                                     int R, int C) {
    __shared__ float tile[32][33];
    int b = blockIdx.z;
    int r0 = blockIdx.y * 32, c0 = blockIdx.x * 32;
    int tx = threadIdx.x, ty = threadIdx.y;
    const float* ip = in + (size_t)b * R * C;
    __hip_bfloat16* op = out + (size_t)b * R * C;
#pragma unroll
    for (int j = 0; j < 32; j += 8)
        tile[ty + j][tx] = ip[(size_t)(r0 + ty + j) * C + (c0 + tx)];
    __syncthreads();
#pragma unroll
    for (int j = 0; j < 32; j += 8)
        op[(size_t)(c0 + ty + j) * R + (r0 + tx)] = __float2bfloat16(tile[tx][ty + j]);
}

// ---------------- QKV GEMM ----------------
// C[4096][3072] = A[4096][1024] @ Bt[3072][1024]^T + bias, then de-interleave
// into K[bh][n][64] (pre-scaled by 1/8), Q[bh][n][64], Vt[bh][64][2048] (bf16).
__global__ __launch_bounds__(256) void gemm_qkv(const __hip_bfloat16* __restrict__ Ag,
                                                const __hip_bfloat16* __restrict__ Btg,
                                                const float* __restrict__ bias,
                                                __hip_bfloat16* __restrict__ Kb,
                                                __hip_bfloat16* __restrict__ Qb,
                                                __hip_bfloat16* __restrict__ Vt) {
    __shared__ __hip_bfloat16 As[64][72];
    __shared__ __hip_bfloat16 Bs[64][72];
    const int t = threadIdx.x;
    const int lane = t & 63, wid = t >> 6;
    const int wm = wid >> 1, wn = wid & 1;
    const int row0 = blockIdx.y * 64, col0 = blockIdx.x * 64;
    const int lr = lane & 15, lg = lane >> 4;
    const int sr = t >> 2, sc = (t & 3) * 16;

    f32x4 acc[2][2] = {};
    for (int k0 = 0; k0 < 1024; k0 += 64) {
        *(uint4*)&As[sr][sc]     = *(const uint4*)&Ag[(size_t)(row0 + sr) * 1024 + k0 + sc];
        *(uint4*)&As[sr][sc + 8] = *(const uint4*)&Ag[(size_t)(row0 + sr) * 1024 + k0 + sc + 8];
        *(uint4*)&Bs[sr][sc]     = *(const uint4*)&Btg[(size_t)(col0 + sr) * 1024 + k0 + sc];
        *(uint4*)&Bs[sr][sc + 8] = *(const uint4*)&Btg[(size_t)(col0 + sr) * 1024 + k0 + sc + 8];
        __syncthreads();
#pragma unroll
        for (int kk = 0; kk < 64; kk += 32) {
            bf16x8 a0 = *(const bf16x8*)&As[wm * 32 + lr][kk + 8 * lg];
            bf16x8 a1 = *(const bf16x8*)&As[wm * 32 + 16 + lr][kk + 8 * lg];
            bf16x8 b0 = *(const bf16x8*)&Bs[wn * 32 + lr][kk + 8 * lg];
            bf16x8 b1 = *(const bf16x8*)&Bs[wn * 32 + 16 + lr][kk + 8 * lg];
            acc[0][0] = MFMA_BF16(a0, b0, acc[0][0], 0, 0, 0);
            acc[0][1] = MFMA_BF16(a0, b1, acc[0][1], 0, 0, 0);
            acc[1][0] = MFMA_BF16(a1, b0, acc[1][0], 0, 0, 0);
            acc[1][1] = MFMA_BF16(a1, b1, acc[1][1], 0, 0, 0);
        }
        __syncthreads();
    }
#pragma unroll
    for (int mt = 0; mt < 2; ++mt)
#pragma unroll
        for (int nt = 0; nt < 2; ++nt)
#pragma unroll
            for (int r = 0; r < 4; ++r) {
                int rg = row0 + wm * 32 + mt * 16 + lg * 4 + r;  // bn index
                int cg = col0 + wn * 32 + nt * 16 + lr;          // h*192+e
                float v = acc[mt][nt][r] + bias[cg];
                int h = cg / 192, e = cg % 192;
                int d = e / 3, which = e % 3;
                int b = rg >> 11, n = rg & 2047;
                int bh = b * 16 + h;
                if (which == 0)      Kb[((size_t)bh * 2048 + n) * 64 + d] = __float2bfloat16(v * 0.125f);
                else if (which == 1) Qb[((size_t)bh * 2048 + n) * 64 + d] = __float2bfloat16(v);
                else                 Vt[((size_t)bh * 64 + d) * 2048 + n] = __float2bfloat16(v);
            }
}

// ---------------- flash attention (swapped-operand 32x32) ----------------
// scores[n][m] = k[n].q[m] (k pre-scaled by 1/8); causal m <= n; sa = softmax_m @ v
// Swapped: S[m][n] = mfma32(A=Q rows m, B=K cols n) -> softmax axis m is in-lane.
// out^T[d][n] = mfma32(A=Vt rows d, B=P cols n).
// 8 waves/block, wave owns 32 output rows; blocks pair chunks z and 15-z so
// every block does exactly 126 m-tiles. grid (8, 32) = 256 blocks = 1/CU.
__global__ __launch_bounds__(512) void attn_fwd(const __hip_bfloat16* __restrict__ Kb,
                                                const __hip_bfloat16* __restrict__ Qb,
                                                const __hip_bfloat16* __restrict__ Vt,
                                                __hip_bfloat16* __restrict__ sa) {
    __shared__ __hip_bfloat16 ot[8][32][66];
    const int zp = blockIdx.x, bh = blockIdx.y;
    const int t = threadIdx.x, lane = t & 63, wid = t >> 6;
    const int col = lane & 31, half = lane >> 5;
    const int chunk = (wid < 4) ? zp : (15 - zp);
    const int n0 = chunk * 128 + (wid & 3) * 32;

    const __hip_bfloat16* Kp = Kb + (size_t)bh * 2048 * 64;
    const __hip_bfloat16* Qp = Qb + (size_t)bh * 2048 * 64;
    const __hip_bfloat16* Vp = Vt + (size_t)bh * 64 * 2048;

    // K fragments (B operand: col = n0+col, k = d), loaded once
    bf16x8 kf[4];
#pragma unroll
    for (int dc = 0; dc < 4; ++dc)
        kf[dc] = *(const bf16x8*)&Kp[(size_t)(n0 + col) * 64 + dc * 16 + 8 * half];

    f32x16 acc0 = {}, acc1 = {};
    float m_run = -3.0e29f, l_run = 0.f;
    const int ng = n0 + col;

    for (int m0 = 0; m0 <= n0 + 31; m0 += 64) {
        // ---- S = Q-tile @ K  (two 32-row m subtiles) ----
        f32x16 s0 = {}, s1 = {};
#pragma unroll
        for (int dc = 0; dc < 4; ++dc) {
            bf16x8 q0 = *(const bf16x8*)&Qp[(size_t)(m0 + col) * 64 + dc * 16 + 8 * half];
            s0 = MFMA32(q0, kf[dc], s0, 0, 0, 0);
        }
#pragma unroll
        for (int dc = 0; dc < 4; ++dc) {
            bf16x8 q1 = *(const bf16x8*)&Qp[(size_t)(m0 + 32 + col) * 64 + dc * 16 + 8 * half];
            s1 = MFMA32(q1, kf[dc], s1, 0, 0, 0);
        }
        // ---- causal mask (only near-diagonal tiles) ----
        if (m0 + 63 > n0) {
            const int mb = m0 + 4 * half;
#pragma unroll
            for (int r = 0; r < 16; ++r) {
                int mg = mb + (r & 3) + 8 * (r >> 2);
                if (mg > ng)      s0[r] = -1e30f;
                if (mg + 32 > ng) s1[r] = -1e30f;
            }
        }
        // ---- online softmax over m: in-lane 32 + one cross-half shuffle ----
        float mx = s0[0];
#pragma unroll
        for (int r = 1; r < 16; ++r) mx = fmaxf(mx, s0[r]);
#pragma unroll
        for (int r = 0; r < 16; ++r) mx = fmaxf(mx, s1[r]);
        mx = fmaxf(mx, __shfl_xor(mx, 32));
        float nm = fmaxf(m_run, mx);
        float scale = __expf(m_run - nm);
        m_run = nm;
        float rs = 0.f;
#pragma unroll
        for (int r = 0; r < 16; ++r) { s0[r] = __expf(s0[r] - nm); rs += s0[r]; }
#pragma unroll
        for (int r = 0; r < 16; ++r) { s1[r] = __expf(s1[r] - nm); rs += s1[r]; }
        rs += __shfl_xor(rs, 32);
        l_run = l_run * scale + rs;
        acc0 *= scale;
        acc1 *= scale;

        // ---- P -> bf16 B-frags in-register, PV accumulate ----
#pragma unroll
        for (int kc = 0; kc < 4; ++kc) {
            float p0, p1, p2, p3, p4, p5, p6, p7;
            if (kc == 0)      { p0=s0[0]; p1=s0[1]; p2=s0[2]; p3=s0[3]; p4=s0[4]; p5=s0[5]; p6=s0[6]; p7=s0[7]; }
            else if (kc == 1) { p0=s0[8]; p1=s0[9]; p2=s0[10]; p3=s0[11]; p4=s0[12]; p5=s0[13]; p6=s0[14]; p7=s0[15]; }
            else if (kc == 2) { p0=s1[0]; p1=s1[1]; p2=s1[2]; p3=s1[3]; p4=s1[4]; p5=s1[5]; p6=s1[6]; p7=s1[7]; }
            else              { p0=s1[8]; p1=s1[9]; p2=s1[10]; p3=s1[11]; p4=s1[12]; p5=s1[13]; p6=s1[14]; p7=s1[15]; }
            unsigned a0 = cvtpk(p0, p1), a1 = cvtpk(p2, p3);
            unsigned a2 = cvtpk(p4, p5), a3 = cvtpk(p6, p7);
            unsigned t0 = __shfl_xor(a0, 32), t1 = __shfl_xor(a1, 32);
            unsigned t2 = __shfl_xor(a2, 32), t3 = __shfl_xor(a3, 32);
            union { unsigned u[4]; bf16x8 v; } pb;
            pb.u[0] = half ? t2 : a0;
            pb.u[1] = half ? t3 : a1;
            pb.u[2] = half ? a2 : t0;
            pb.u[3] = half ? a3 : t1;
            bf16x8 va0 = *(const bf16x8*)&Vp[(size_t)(col) * 2048 + m0 + kc * 16 + 8 * half];
            bf16x8 va1 = *(const bf16x8*)&Vp[(size_t)(32 + col) * 2048 + m0 + kc * 16 + 8 * half];
            acc0 = MFMA32(va0, pb.v, acc0, 0, 0, 0);
            acc1 = MFMA32(va1, pb.v, acc1, 0, 0, 0);
        }
    }

    // ---- epilogue: normalize, transpose via LDS, coalesced store ----
    float inv = 1.0f / l_run;
#pragma unroll
    for (int r = 0; r < 16; ++r) {
        int d0 = (r & 3) + 8 * (r >> 2) + 4 * half;
        ot[wid][col][d0]      = __float2bfloat16(acc0[r] * inv);
        ot[wid][col][32 + d0] = __float2bfloat16(acc1[r] * inv);
    }
    const int b = bh >> 4, h = bh & 15;
#pragma unroll
    for (int tt = 0; tt < 16; ++tt) {
        int rrow = tt * 2 + half;
        unsigned v = *(const unsigned*)&ot[wid][rrow][col * 2];
        *(unsigned*)&sa[((size_t)(b * 2048 + n0 + rrow)) * 1024 + h * 64 + col * 2] = v;
    }
}

// ---------------- output projection ----------------
__global__ __launch_bounds__(256) void gemm_proj(const __hip_bfloat16* __restrict__ Ag,
                                                 const __hip_bfloat16* __restrict__ Btg,
                                                 const float* __restrict__ bias,
                                                 float* __restrict__ out) {
    __shared__ __hip_bfloat16 As[64][72];
    __shared__ __hip_bfloat16 Bs[64][72];
    const int t = threadIdx.x;
    const int lane = t & 63, wid = t >> 6;
    const int wm = wid >> 1, wn = wid & 1;
    const int row0 = blockIdx.y * 64, col0 = blockIdx.x * 64;
    const int lr = lane & 15, lg = lane >> 4;
    const int sr = t >> 2, sc = (t & 3) * 16;

    f32x4 acc[2][2] = {};
    for (int k0 = 0; k0 < 1024; k0 += 64) {
        *(uint4*)&As[sr][sc]     = *(const uint4*)&Ag[(size_t)(row0 + sr) * 1024 + k0 + sc];
        *(uint4*)&As[sr][sc + 8] = *(const uint4*)&Ag[(size_t)(row0 + sr) * 1024 + k0 + sc + 8];
        *(uint4*)&Bs[sr][sc]     = *(const uint4*)&Btg[(size_t)(col0 + sr) * 1024 + k0 + sc];
        *(uint4*)&Bs[sr][sc + 8] = *(const uint4*)&Btg[(size_t)(col0 + sr) * 1024 + k0 + sc + 8];
        __syncthreads();
#pragma unroll
        for (int kk = 0; kk < 64; kk += 32) {
            bf16x8 a0 = *(const bf16x8*)&As[wm * 32 + lr][kk + 8 * lg];
            bf16x8 a1 = *(const bf16x8*)&As[wm * 32 + 16 + lr][kk + 8 * lg];
            bf16x8 b0 = *(const bf16x8*)&Bs[wn * 32 + lr][kk + 8 * lg];
            bf16x8 b1 = *(const bf16x8*)&Bs[wn * 32 + 16 + lr][kk + 8 * lg];
            acc[0][0] = MFMA_BF16(a0, b0, acc[0][0], 0, 0, 0);
            acc[0][1] = MFMA_BF16(a0, b1, acc[0][1], 0, 0, 0);
            acc[1][0] = MFMA_BF16(a1, b0, acc[1][0], 0, 0, 0);
            acc[1][1] = MFMA_BF16(a1, b1, acc[1][1], 0, 0, 0);
        }
        __syncthreads();
    }
#pragma unroll
    for (int mt = 0; mt < 2; ++mt)
#pragma unroll
        for (int nt = 0; nt < 2; ++nt)
#pragma unroll
            for (int r = 0; r < 4; ++r) {
                int rg = row0 + wm * 32 + mt * 16 + lg * 4 + r;
                int cg = col0 + wn * 32 + nt * 16 + lr;
                out[(size_t)rg * 1024 + cg] = acc[mt][nt][r] + bias[cg];
            }
}

// ---------------- launch ----------------
extern "C" void kernel_launch(void* const* d_in, const int* in_sizes, int n_in,
                              void* d_out, int out_size, void* d_ws, size_t ws_size,
                              hipStream_t stream) {
    const float* x     = (const float*)d_in[0];  // [2,2048,1024]
    const float* Wkqv  = (const float*)d_in[1];  // [16,1024,192]
    const float* bkqv  = (const float*)d_in[2];  // [16,192] -> flat [3072]
    const float* Wproj = (const float*)d_in[3];  // [1024,1024]
    const float* bproj = (const float*)d_in[4];  // [1024]

    char* w = (char*)d_ws;
    // workspace layout (bytes)
    __hip_bfloat16* xb  = (__hip_bfloat16*)(w + 0);          //  8388608
    __hip_bfloat16* Wt  = (__hip_bfloat16*)(w + 8388608);    //  6291456  [16][192][1024]
    __hip_bfloat16* WpT = (__hip_bfloat16*)(w + 14680064);   //  2097152  [1024][1024]
    __hip_bfloat16* Kb  = (__hip_bfloat16*)(w + 16777216);   //  8388608  [32][2048][64], pre-scaled 1/8
    __hip_bfloat16* Qb  = (__hip_bfloat16*)(w + 25165824);   //  8388608
    __hip_bfloat16* Vt  = (__hip_bfloat16*)(w + 33554432);   //  8388608  [32][64][2048]
    __hip_bfloat16* sab = (__hip_bfloat16*)(w + 41943040);   //  8388608  [4096][1024]
    if (ws_size < 50331648) return;

    cvt_f32_bf16<<<4096, 256, 0, stream>>>(x, xb);
    transpose_cvt<<<dim3(6, 32, 16), dim3(32, 8), 0, stream>>>(Wkqv, Wt, 1024, 192);
    transpose_cvt<<<dim3(32, 32, 1), dim3(32, 8), 0, stream>>>(Wproj, WpT, 1024, 1024);
    gemm_qkv<<<dim3(48, 64), 256, 0, stream>>>(xb, Wt, bkqv, Kb, Qb, Vt);
    attn_fwd<<<dim3(8, 32), 512, 0, stream>>>(Kb, Qb, Vt, sab);
    gemm_proj<<<dim3(16, 64), 256, 0, stream>>>(sab, WpT, bproj, (float*)d_out);
}

// Round 3
// 189.106 us; speedup vs baseline: 1.8043x; 1.0269x over previous
//
#include <hip/hip_runtime.h>
#include <hip/hip_bf16.h>

// Problem dims (fixed)
// B=2, N=2048, D=1024, H=16, DK=64
// x: [2,2048,1024] f32; Wkqv: [16,1024,192] f32; bkqv: [16,192] f32;
// Wproj: [1024,1024] f32; bproj: [1024] f32; out: [2,2048,1024] f32

typedef __bf16 bf16x8 __attribute__((ext_vector_type(8)));
typedef float f32x4 __attribute__((ext_vector_type(4)));
typedef float f32x16 __attribute__((ext_vector_type(16)));

#define MFMA_BF16 __builtin_amdgcn_mfma_f32_16x16x32_bf16
#define MFMA32 __builtin_amdgcn_mfma_f32_32x32x16_bf16

static __device__ __forceinline__ unsigned cvtpk(float lo, float hi) {
    unsigned r;
    asm("v_cvt_pk_bf16_f32 %0, %1, %2" : "=v"(r) : "v"(lo), "v"(hi));
    return r;
}

// async global -> LDS, 16 B per lane; lds base must be wave-uniform
static __device__ __forceinline__ void gld16(const void* g, void* l) {
    __builtin_amdgcn_global_load_lds(
        (const __attribute__((address_space(1))) unsigned int*)g,
        (__attribute__((address_space(3))) unsigned int*)l, 16, 0, 0);
}

// ---------------- prep kernels ----------------

__global__ __launch_bounds__(256) void cvt_f32_bf16(const float* __restrict__ in,
                                                    __hip_bfloat16* __restrict__ out) {
    int i = (blockIdx.x * 256 + threadIdx.x) * 4;
    float4 v = *(const float4*)&in[i];
    struct alignas(8) bh4 { __hip_bfloat16 a, b, c, d; };
    bh4 r{__float2bfloat16(v.x), __float2bfloat16(v.y),
          __float2bfloat16(v.z), __float2bfloat16(v.w)};
    *(bh4*)&out[i] = r;
}

// in [b][R][C] f32 -> out [b][C][R] bf16 ; 32x32 tiles, block (32,8)
__global__ __launch_bounds__(256) void transpose_cvt(const float* __restrict__ in,
                                                     __hip_bfloat16* __restrict__ out,
                                                     int R, int C) {
    __shared__ float tile[32][33];
    int b = blockIdx.z;
    int r0 = blockIdx.y * 32, c0 = blockIdx.x * 32;
    int tx = threadIdx.x, ty = threadIdx.y;
    const float* ip = in + (size_t)b * R * C;
    __hip_bfloat16* op = out + (size_t)b * R * C;
#pragma unroll
    for (int j = 0; j < 32; j += 8)
        tile[ty + j][tx] = ip[(size_t)(r0 + ty + j) * C + (c0 + tx)];
    __syncthreads();
#pragma unroll
    for (int j = 0; j < 32; j += 8)
        op[(size_t)(c0 + ty + j) * R + (r0 + tx)] = __float2bfloat16(tile[tx][ty + j]);
}

// ---------------- QKV GEMM (m97-style 128x128, BK=64, global_load_lds) ----
// C[4096][3072] = A[4096][1024] @ Bt[3072][1024]^T + bias, de-interleaved into
// K[bh][n][64] (pre-scaled 1/8), Q[bh][n][64], Vt[bh][64][2048] (bf16).
__global__ __launch_bounds__(256) void gemm_qkv(const __hip_bfloat16* __restrict__ Ag,
                                                const __hip_bfloat16* __restrict__ Btg,
                                                const float* __restrict__ bias,
                                                __hip_bfloat16* __restrict__ Kb,
                                                __hip_bfloat16* __restrict__ Qb,
                                                __hip_bfloat16* __restrict__ Vt) {
    __shared__ __hip_bfloat16 As[128 * 64];
    __shared__ __hip_bfloat16 Bs[128 * 64];
    const int t = threadIdx.x;
    const int lane = t & 63, wid = t >> 6;
    const int wm = wid >> 1, wn = wid & 1;
    const int row0 = blockIdx.y * 128, col0 = blockIdx.x * 128;
    const int lr = lane & 15, lg = lane >> 4;
    const int srow = wid * 8 + (lane >> 3);  // row within 32-row c-block
    const int scol = (lane & 7) * 8;         // elem col (16B granules)

    f32x4 acc[4][4] = {};
    for (int k0 = 0; k0 < 1024; k0 += 64) {
#pragma unroll
        for (int c = 0; c < 4; ++c) {
            gld16(&Ag[(size_t)(row0 + c * 32 + srow) * 1024 + k0 + scol],
                  &As[(c * 32 + wid * 8) * 64]);
            gld16(&Btg[(size_t)(col0 + c * 32 + srow) * 1024 + k0 + scol],
                  &Bs[(c * 32 + wid * 8) * 64]);
        }
        __syncthreads();
#pragma unroll
        for (int kk = 0; kk < 64; kk += 32) {
            bf16x8 af[4], bfr[4];
#pragma unroll
            for (int i = 0; i < 4; ++i)
                af[i] = *(const bf16x8*)&As[(wm * 64 + i * 16 + lr) * 64 + kk + 8 * lg];
#pragma unroll
            for (int j = 0; j < 4; ++j)
                bfr[j] = *(const bf16x8*)&Bs[(wn * 64 + j * 16 + lr) * 64 + kk + 8 * lg];
#pragma unroll
            for (int i = 0; i < 4; ++i)
#pragma unroll
                for (int j = 0; j < 4; ++j)
                    acc[i][j] = MFMA_BF16(af[i], bfr[j], acc[i][j], 0, 0, 0);
        }
        __syncthreads();
    }
#pragma unroll
    for (int i = 0; i < 4; ++i)
#pragma unroll
        for (int j = 0; j < 4; ++j)
#pragma unroll
            for (int r = 0; r < 4; ++r) {
                int rg = row0 + wm * 64 + i * 16 + lg * 4 + r;  // bn index
                int cg = col0 + wn * 64 + j * 16 + lr;          // h*192+e
                float v = acc[i][j][r] + bias[cg];
                int h = cg / 192, e = cg % 192;
                int d = e / 3, which = e % 3;
                int b = rg >> 11, n = rg & 2047;
                int bh = b * 16 + h;
                if (which == 0)      Kb[((size_t)bh * 2048 + n) * 64 + d] = __float2bfloat16(v * 0.125f);
                else if (which == 1) Qb[((size_t)bh * 2048 + n) * 64 + d] = __float2bfloat16(v);
                else                 Vt[((size_t)bh * 64 + d) * 2048 + n] = __float2bfloat16(v);
            }
}

// ---------------- flash attention (swapped 32x32, 2-way m-split) ----------
// S[m][n] = mfma32(A=Q rows m, B=K cols n); softmax axis m in-lane.
// Each 32-row n-slice handled by 2 waves (even/odd m-tiles), merged via LDS.
// Block: 4 waves = slices {zp, 63-zp} x parity. grid (32, 32) = 1024 blocks.
__global__ __launch_bounds__(256) void attn_fwd(const __hip_bfloat16* __restrict__ Kb,
                                                const __hip_bfloat16* __restrict__ Qb,
                                                const __hip_bfloat16* __restrict__ Vt,
                                                __hip_bfloat16* __restrict__ sa) {
    __shared__ float mbuf[2][64][35];
    __shared__ __hip_bfloat16 ot[2][32][66];
    const int zp = blockIdx.x, bh = blockIdx.y;
    const int t = threadIdx.x, lane = t & 63, wid = t >> 6;
    const int col = lane & 31, half = lane >> 5;
    const int sl = wid >> 1, par = wid & 1;
    const int slice = sl ? (63 - zp) : zp;
    const int n0 = slice * 32;

    const __hip_bfloat16* Kp = Kb + (size_t)bh * 2048 * 64;
    const __hip_bfloat16* Qp = Qb + (size_t)bh * 2048 * 64;
    const __hip_bfloat16* Vp = Vt + (size_t)bh * 64 * 2048;

    // K fragments (B operand: col = n0+col, k = d), loaded once
    bf16x8 kf[4];
#pragma unroll
    for (int dc = 0; dc < 4; ++dc)
        kf[dc] = *(const bf16x8*)&Kp[(size_t)(n0 + col) * 64 + dc * 16 + 8 * half];

    f32x16 acc0 = {}, acc1 = {};
    float m_run = -3.0e29f, l_run = 0.f;
    const int ng = n0 + col;
    const int T = (n0 + 95) >> 6;  // number of 64-wide m tiles for this slice

    for (int j = par; j < T; j += 2) {
        const int m0 = j << 6;
        // ---- S = Q-tile @ K  (two 32-row m subtiles) ----
        f32x16 s0 = {}, s1 = {};
#pragma unroll
        for (int dc = 0; dc < 4; ++dc) {
            bf16x8 q0 = *(const bf16x8*)&Qp[(size_t)(m0 + col) * 64 + dc * 16 + 8 * half];
            s0 = MFMA32(q0, kf[dc], s0, 0, 0, 0);
        }
#pragma unroll
        for (int dc = 0; dc < 4; ++dc) {
            bf16x8 q1 = *(const bf16x8*)&Qp[(size_t)(m0 + 32 + col) * 64 + dc * 16 + 8 * half];
            s1 = MFMA32(q1, kf[dc], s1, 0, 0, 0);
        }
        // ---- causal mask (only near-diagonal tiles) ----
        if (m0 + 63 > n0) {
            const int mb = m0 + 4 * half;
#pragma unroll
            for (int r = 0; r < 16; ++r) {
                int mg = mb + (r & 3) + 8 * (r >> 2);
                if (mg > ng)      s0[r] = -1e30f;
                if (mg + 32 > ng) s1[r] = -1e30f;
            }
        }
        // ---- online softmax over m ----
        float mx = s0[0];
#pragma unroll
        for (int r = 1; r < 16; ++r) mx = fmaxf(mx, s0[r]);
#pragma unroll
        for (int r = 0; r < 16; ++r) mx = fmaxf(mx, s1[r]);
        mx = fmaxf(mx, __shfl_xor(mx, 32));
        float nm = fmaxf(m_run, mx);
        float scale = __expf(m_run - nm);
        m_run = nm;
        float rs = 0.f;
#pragma unroll
        for (int r = 0; r < 16; ++r) { s0[r] = __expf(s0[r] - nm); rs += s0[r]; }
#pragma unroll
        for (int r = 0; r < 16; ++r) { s1[r] = __expf(s1[r] - nm); rs += s1[r]; }
        rs += __shfl_xor(rs, 32);
        l_run = l_run * scale + rs;
        acc0 *= scale;
        acc1 *= scale;

        // ---- P -> bf16 B-frags in-register, PV accumulate ----
#pragma unroll
        for (int kc = 0; kc < 4; ++kc) {
            float p0, p1, p2, p3, p4, p5, p6, p7;
            if (kc == 0)      { p0=s0[0]; p1=s0[1]; p2=s0[2]; p3=s0[3]; p4=s0[4]; p5=s0[5]; p6=s0[6]; p7=s0[7]; }
            else if (kc == 1) { p0=s0[8]; p1=s0[9]; p2=s0[10]; p3=s0[11]; p4=s0[12]; p5=s0[13]; p6=s0[14]; p7=s0[15]; }
            else if (kc == 2) { p0=s1[0]; p1=s1[1]; p2=s1[2]; p3=s1[3]; p4=s1[4]; p5=s1[5]; p6=s1[6]; p7=s1[7]; }
            else              { p0=s1[8]; p1=s1[9]; p2=s1[10]; p3=s1[11]; p4=s1[12]; p5=s1[13]; p6=s1[14]; p7=s1[15]; }
            unsigned a0 = cvtpk(p0, p1), a1 = cvtpk(p2, p3);
            unsigned a2 = cvtpk(p4, p5), a3 = cvtpk(p6, p7);
            unsigned t0 = __shfl_xor(a0, 32), t1 = __shfl_xor(a1, 32);
            unsigned t2 = __shfl_xor(a2, 32), t3 = __shfl_xor(a3, 32);
            union { unsigned u[4]; bf16x8 v; } pb;
            pb.u[0] = half ? t2 : a0;
            pb.u[1] = half ? t3 : a1;
            pb.u[2] = half ? a2 : t0;
            pb.u[3] = half ? a3 : t1;
            bf16x8 va0 = *(const bf16x8*)&Vp[(size_t)(col) * 2048 + m0 + kc * 16 + 8 * half];
            bf16x8 va1 = *(const bf16x8*)&Vp[(size_t)(32 + col) * 2048 + m0 + kc * 16 + 8 * half];
            acc0 = MFMA32(va0, pb.v, acc0, 0, 0, 0);
            acc1 = MFMA32(va1, pb.v, acc1, 0, 0, 0);
        }
    }

    // ---- merge the two partial states of each slice ----
    if (par) {
#pragma unroll
        for (int r = 0; r < 16; ++r) {
            mbuf[sl][lane][r]      = acc0[r];
            mbuf[sl][lane][16 + r] = acc1[r];
        }
        mbuf[sl][lane][32] = m_run;
        mbuf[sl][lane][33] = l_run;
    }
    __syncthreads();
    if (!par) {
        float mB = mbuf[sl][lane][32], lB = mbuf[sl][lane][33];
        float nm = fmaxf(m_run, mB);
        float sA = __expf(m_run - nm), sB = __expf(mB - nm);
        float l = l_run * sA + lB * sB;
#pragma unroll
        for (int r = 0; r < 16; ++r) {
            acc0[r] = acc0[r] * sA + mbuf[sl][lane][r] * sB;
            acc1[r] = acc1[r] * sA + mbuf[sl][lane][16 + r] * sB;
        }
        // ---- epilogue: normalize, transpose via LDS, coalesced store ----
        float inv = 1.0f / l;
#pragma unroll
        for (int r = 0; r < 16; ++r) {
            int d0 = (r & 3) + 8 * (r >> 2) + 4 * half;
            ot[sl][col][d0]      = __float2bfloat16(acc0[r] * inv);
            ot[sl][col][32 + d0] = __float2bfloat16(acc1[r] * inv);
        }
        const int b = bh >> 4, h = bh & 15;
#pragma unroll
        for (int tt = 0; tt < 16; ++tt) {
            int rrow = tt * 2 + half;
            unsigned v = *(const unsigned*)&ot[sl][rrow][col * 2];
            *(unsigned*)&sa[((size_t)(b * 2048 + n0 + rrow)) * 1024 + h * 64 + col * 2] = v;
        }
    }
}

// ---------------- output projection (m97-style 128x128) ----------------
__global__ __launch_bounds__(256) void gemm_proj(const __hip_bfloat16* __restrict__ Ag,
                                                 const __hip_bfloat16* __restrict__ Btg,
                                                 const float* __restrict__ bias,
                                                 float* __restrict__ out) {
    __shared__ __hip_bfloat16 As[128 * 64];
    __shared__ __hip_bfloat16 Bs[128 * 64];
    const int t = threadIdx.x;
    const int lane = t & 63, wid = t >> 6;
    const int wm = wid >> 1, wn = wid & 1;
    const int row0 = blockIdx.y * 128, col0 = blockIdx.x * 128;
    const int lr = lane & 15, lg = lane >> 4;
    const int srow = wid * 8 + (lane >> 3);
    const int scol = (lane & 7) * 8;

    f32x4 acc[4][4] = {};
    for (int k0 = 0; k0 < 1024; k0 += 64) {
#pragma unroll
        for (int c = 0; c < 4; ++c) {
            gld16(&Ag[(size_t)(row0 + c * 32 + srow) * 1024 + k0 + scol],
                  &As[(c * 32 + wid * 8) * 64]);
            gld16(&Btg[(size_t)(col0 + c * 32 + srow) * 1024 + k0 + scol],
                  &Bs[(c * 32 + wid * 8) * 64]);
        }
        __syncthreads();
#pragma unroll
        for (int kk = 0; kk < 64; kk += 32) {
            bf16x8 af[4], bfr[4];
#pragma unroll
            for (int i = 0; i < 4; ++i)
                af[i] = *(const bf16x8*)&As[(wm * 64 + i * 16 + lr) * 64 + kk + 8 * lg];
#pragma unroll
            for (int j = 0; j < 4; ++j)
                bfr[j] = *(const bf16x8*)&Bs[(wn * 64 + j * 16 + lr) * 64 + kk + 8 * lg];
#pragma unroll
            for (int i = 0; i < 4; ++i)
#pragma unroll
                for (int j = 0; j < 4; ++j)
                    acc[i][j] = MFMA_BF16(af[i], bfr[j], acc[i][j], 0, 0, 0);
        }
        __syncthreads();
    }
#pragma unroll
    for (int i = 0; i < 4; ++i)
#pragma unroll
        for (int j = 0; j < 4; ++j)
#pragma unroll
            for (int r = 0; r < 4; ++r) {
                int rg = row0 + wm * 64 + i * 16 + lg * 4 + r;
                int cg = col0 + wn * 64 + j * 16 + lr;
                out[(size_t)rg * 1024 + cg] = acc[i][j][r] + bias[cg];
            }
}

// ---------------- launch ----------------
extern "C" void kernel_launch(void* const* d_in, const int* in_sizes, int n_in,
                              void* d_out, int out_size, void* d_ws, size_t ws_size,
                              hipStream_t stream) {
    const float* x     = (const float*)d_in[0];  // [2,2048,1024]
    const float* Wkqv  = (const float*)d_in[1];  // [16,1024,192]
    const float* bkqv  = (const float*)d_in[2];  // [16,192] -> flat [3072]
    const float* Wproj = (const float*)d_in[3];  // [1024,1024]
    const float* bproj = (const float*)d_in[4];  // [1024]

    char* w = (char*)d_ws;
    // workspace layout (bytes)
    __hip_bfloat16* xb  = (__hip_bfloat16*)(w + 0);          //  8388608
    __hip_bfloat16* Wt  = (__hip_bfloat16*)(w + 8388608);    //  6291456  [16][192][1024]
    __hip_bfloat16* WpT = (__hip_bfloat16*)(w + 14680064);   //  2097152  [1024][1024]
    __hip_bfloat16* Kb  = (__hip_bfloat16*)(w + 16777216);   //  8388608  [32][2048][64], pre-scaled 1/8
    __hip_bfloat16* Qb  = (__hip_bfloat16*)(w + 25165824);   //  8388608
    __hip_bfloat16* Vt  = (__hip_bfloat16*)(w + 33554432);   //  8388608  [32][64][2048]
    __hip_bfloat16* sab = (__hip_bfloat16*)(w + 41943040);   //  8388608  [4096][1024]
    if (ws_size < 50331648) return;

    cvt_f32_bf16<<<4096, 256, 0, stream>>>(x, xb);
    transpose_cvt<<<dim3(6, 32, 16), dim3(32, 8), 0, stream>>>(Wkqv, Wt, 1024, 192);
    transpose_cvt<<<dim3(32, 32, 1), dim3(32, 8), 0, stream>>>(Wproj, WpT, 1024, 1024);
    gemm_qkv<<<dim3(24, 32), 256, 0, stream>>>(xb, Wt, bkqv, Kb, Qb, Vt);
    attn_fwd<<<dim3(32, 32), 256, 0, stream>>>(Kb, Qb, Vt, sab);
    gemm_proj<<<dim3(8, 32), 256, 0, stream>>>(sab, WpT, bproj, (float*)d_out);
}

// Round 4
// 183.717 us; speedup vs baseline: 1.8572x; 1.0293x over previous
//
#include <hip/hip_runtime.h>
#include <hip/hip_bf16.h>

// Problem dims (fixed)
// B=2, N=2048, D=1024, H=16, DK=64
// x: [2,2048,1024] f32; Wkqv: [16,1024,192] f32; bkqv: [16,192] f32;
// Wproj: [1024,1024] f32; bproj: [1024] f32; out: [2,2048,1024] f32

typedef __bf16 bf16x8 __attribute__((ext_vector_type(8)));
typedef float f32x4 __attribute__((ext_vector_type(4)));
typedef float f32x16 __attribute__((ext_vector_type(16)));

#define MFMA_BF16 __builtin_amdgcn_mfma_f32_16x16x32_bf16
#define MFMA32 __builtin_amdgcn_mfma_f32_32x32x16_bf16

static __device__ __forceinline__ unsigned cvtpk(float lo, float hi) {
    unsigned r;
    asm("v_cvt_pk_bf16_f32 %0, %1, %2" : "=v"(r) : "v"(lo), "v"(hi));
    return r;
}

// async global -> LDS, 16 B per lane; lds base must be wave-uniform
static __device__ __forceinline__ void gld16(const void* g, void* l) {
    __builtin_amdgcn_global_load_lds(
        (const __attribute__((address_space(1))) unsigned int*)g,
        (__attribute__((address_space(3))) unsigned int*)l, 16, 0, 0);
}

// ---------------- prep kernels ----------------

__global__ __launch_bounds__(256) void cvt_f32_bf16(const float* __restrict__ in,
                                                    __hip_bfloat16* __restrict__ out) {
    int i = (blockIdx.x * 256 + threadIdx.x) * 4;
    float4 v = *(const float4*)&in[i];
    struct alignas(8) bh4 { __hip_bfloat16 a, b, c, d; };
    bh4 r{__float2bfloat16(v.x), __float2bfloat16(v.y),
          __float2bfloat16(v.z), __float2bfloat16(v.w)};
    *(bh4*)&out[i] = r;
}

// in [b][R][C] f32 -> out [b][C][R] bf16 ; 32x32 tiles, block (32,8)
__global__ __launch_bounds__(256) void transpose_cvt(const float* __restrict__ in,
                                                     __hip_bfloat16* __restrict__ out,
                                                     int R, int C) {
    __shared__ float tile[32][33];
    int b = blockIdx.z;
    int r0 = blockIdx.y * 32, c0 = blockIdx.x * 32;
    int tx = threadIdx.x, ty = threadIdx.y;
    const float* ip = in + (size_t)b * R * C;
    __hip_bfloat16* op = out + (size_t)b * R * C;
#pragma unroll
    for (int j = 0; j < 32; j += 8)
        tile[ty + j][tx] = ip[(size_t)(r0 + ty + j) * C + (c0 + tx)];
    __syncthreads();
#pragma unroll
    for (int j = 0; j < 32; j += 8)
        op[(size_t)(c0 + ty + j) * R + (r0 + tx)] = __float2bfloat16(tile[tx][ty + j]);
}

// ---------------- QKV GEMM (128x128, BK=64, global_load_lds) ----
// C[4096][3072] = A[4096][1024] @ Bt[3072][1024]^T + bias (cols cg%3==0 also
// pre-scaled by 1/8 = the K score scale). Plain coalesced bf16 output.
__global__ __launch_bounds__(256) void gemm_qkv(const __hip_bfloat16* __restrict__ Ag,
                                                const __hip_bfloat16* __restrict__ Btg,
                                                const float* __restrict__ bias,
                                                __hip_bfloat16* __restrict__ C) {
    __shared__ __hip_bfloat16 As[128 * 64];
    __shared__ __hip_bfloat16 Bs[128 * 64];
    const int t = threadIdx.x;
    const int lane = t & 63, wid = t >> 6;
    const int wm = wid >> 1, wn = wid & 1;
    const int row0 = blockIdx.y * 128, col0 = blockIdx.x * 128;
    const int lr = lane & 15, lg = lane >> 4;
    const int srow = wid * 8 + (lane >> 3);
    const int scol = (lane & 7) * 8;

    f32x4 acc[4][4] = {};
    for (int k0 = 0; k0 < 1024; k0 += 64) {
#pragma unroll
        for (int c = 0; c < 4; ++c) {
            gld16(&Ag[(size_t)(row0 + c * 32 + srow) * 1024 + k0 + scol],
                  &As[(c * 32 + wid * 8) * 64]);
            gld16(&Btg[(size_t)(col0 + c * 32 + srow) * 1024 + k0 + scol],
                  &Bs[(c * 32 + wid * 8) * 64]);
        }
        __syncthreads();
#pragma unroll
        for (int kk = 0; kk < 64; kk += 32) {
            bf16x8 af[4], bfr[4];
#pragma unroll
            for (int i = 0; i < 4; ++i)
                af[i] = *(const bf16x8*)&As[(wm * 64 + i * 16 + lr) * 64 + kk + 8 * lg];
#pragma unroll
            for (int j = 0; j < 4; ++j)
                bfr[j] = *(const bf16x8*)&Bs[(wn * 64 + j * 16 + lr) * 64 + kk + 8 * lg];
#pragma unroll
            for (int i = 0; i < 4; ++i)
#pragma unroll
                for (int j = 0; j < 4; ++j)
                    acc[i][j] = MFMA_BF16(af[i], bfr[j], acc[i][j], 0, 0, 0);
        }
        __syncthreads();
    }
#pragma unroll
    for (int i = 0; i < 4; ++i)
#pragma unroll
        for (int j = 0; j < 4; ++j)
#pragma unroll
            for (int r = 0; r < 4; ++r) {
                int rg = row0 + wm * 64 + i * 16 + lg * 4 + r;
                int cg = col0 + wn * 64 + j * 16 + lr;
                float v = acc[i][j][r] + bias[cg];
                if (cg % 3 == 0) v *= 0.125f;  // K pre-scale
                C[(size_t)rg * 3072 + cg] = __float2bfloat16(v);
            }
}

// ---------------- repack C -> fragment-major K/Q/V ----------------
// Block = (mt, bh): rows b*2048 + mt*64 .. +64, cols h*192 .. +192 of C.
// Kf[bh][slice(64)][dc(4)][lane(64)][i(8)]  elem = K[bh][slice*32+(l&31)][dc*16+8*(l>>5)+i]
// Qf[bh][mt(32)][sub(2)][dc(4)][lane(64)][i(8)] elem = Q[bh][mt*64+sub*32+(l&31)][dc*16+8*(l>>5)+i]
// Vf[bh][mt(32)][kc(4)][accN(2)][lane(64)][i(8)] elem = V[bh][mt*64+kc*16+8*(l>>5)+i][accN*32+(l&31)]
// with K col = d*3, Q col = d*3+1, V col = d*3+2 inside the 192-wide head slab.
__global__ __launch_bounds__(256) void repack_qkv(const __hip_bfloat16* __restrict__ C,
                                                  __hip_bfloat16* __restrict__ Kf,
                                                  __hip_bfloat16* __restrict__ Qf,
                                                  __hip_bfloat16* __restrict__ Vf) {
    __shared__ __hip_bfloat16 tile[64][200];
    const int mt = blockIdx.x, bh = blockIdx.y;
    const int b = bh >> 4, h = bh & 15;
    const __hip_bfloat16* Cp = C + ((size_t)(b * 2048 + mt * 64)) * 3072 + h * 192;
    const int t = threadIdx.x;
#pragma unroll
    for (int r = 0; r < 6; ++r) {
        int idx = t + 256 * r;
        int row = idx / 24, seg = idx % 24;
        *(uint4*)&tile[row][seg * 8] = *(const uint4*)&Cp[(size_t)row * 3072 + seg * 8];
    }
    __syncthreads();
    const size_t qbase = ((size_t)bh * 32 + mt) * 4096;
    const size_t kbase = ((size_t)bh * 64 + mt * 2) * 2048;
    const size_t vbase = ((size_t)bh * 32 + mt) * 4096;
#pragma unroll
    for (int c = 0; c < 2; ++c) {
        int chunk = t + 256 * c;
        int l = chunk & 63, blk = chunk >> 6;
        int hi = l >> 5, lo = l & 31;
        // Q: blk = sub*4 + dc
        {
            int sub = blk >> 2, dc = blk & 3;
            int row = sub * 32 + lo, dbase = dc * 16 + 8 * hi;
            ushort u[8];
#pragma unroll
            for (int i = 0; i < 8; ++i)
                u[i] = *(const ushort*)&tile[row][(dbase + i) * 3 + 1];
            *(uint4*)&Qf[qbase + (size_t)chunk * 8] = *(const uint4*)u;
        }
        // K: blk = sub2*4 + dc  (two slices per mt)
        {
            int sub2 = blk >> 2, dc = blk & 3;
            int row = sub2 * 32 + lo, dbase = dc * 16 + 8 * hi;
            ushort u[8];
#pragma unroll
            for (int i = 0; i < 8; ++i)
                u[i] = *(const ushort*)&tile[row][(dbase + i) * 3];
            *(uint4*)&Kf[kbase + (size_t)chunk * 8] = *(const uint4*)u;
        }
        // V: blk = kc*2 + accN ; row varies with i, col fixed
        {
            int kc = blk >> 1, accN = blk & 1;
            int col = (accN * 32 + lo) * 3 + 2, rbase = kc * 16 + 8 * hi;
            ushort u[8];
#pragma unroll
            for (int i = 0; i < 8; ++i)
                u[i] = *(const ushort*)&tile[rbase + i][col];
            *(uint4*)&Vf[vbase + (size_t)chunk * 8] = *(const uint4*)u;
        }
    }
}

// ---------------- flash attention (swapped 32x32, 2-way m-split) ----------
// Fragment-major operands: every load is base + lane*16B (fully coalesced).
__global__ __launch_bounds__(256) void attn_fwd(const __hip_bfloat16* __restrict__ Kf,
                                                const __hip_bfloat16* __restrict__ Qf,
                                                const __hip_bfloat16* __restrict__ Vf,
                                                __hip_bfloat16* __restrict__ sa) {
    __shared__ float mbuf[2][64][35];
    __shared__ __hip_bfloat16 ot[2][32][66];
    const int zp = blockIdx.x, bh = blockIdx.y;
    const int t = threadIdx.x, lane = t & 63, wid = t >> 6;
    const int col = lane & 31, half = lane >> 5;
    const int sl = wid >> 1, par = wid & 1;
    const int slice = sl ? (63 - zp) : zp;
    const int n0 = slice * 32;

    const __hip_bfloat16* Kfp = Kf + (size_t)bh * 131072;
    const __hip_bfloat16* Qfp = Qf + (size_t)bh * 131072;
    const __hip_bfloat16* Vfp = Vf + (size_t)bh * 131072;

    // K fragments, loaded once (coalesced)
    bf16x8 kf[4];
#pragma unroll
    for (int dc = 0; dc < 4; ++dc)
        kf[dc] = *(const bf16x8*)&Kfp[((size_t)slice * 4 + dc) * 512 + lane * 8];

    f32x16 acc0 = {}, acc1 = {};
    float m_run = -3.0e29f, l_run = 0.f;
    const int ng = n0 + col;
    const int T = (n0 + 95) >> 6;  // number of 64-wide m tiles for this slice

    for (int j = par; j < T; j += 2) {
        const int m0 = j << 6;
        // ---- S = Q-tile @ K  (two 32-row m subtiles) ----
        f32x16 s0 = {}, s1 = {};
#pragma unroll
        for (int dc = 0; dc < 4; ++dc) {
            bf16x8 q0 = *(const bf16x8*)&Qfp[(((size_t)j * 2 + 0) * 4 + dc) * 512 + lane * 8];
            s0 = MFMA32(q0, kf[dc], s0, 0, 0, 0);
        }
#pragma unroll
        for (int dc = 0; dc < 4; ++dc) {
            bf16x8 q1 = *(const bf16x8*)&Qfp[(((size_t)j * 2 + 1) * 4 + dc) * 512 + lane * 8];
            s1 = MFMA32(q1, kf[dc], s1, 0, 0, 0);
        }
        // ---- causal mask (only near-diagonal tiles) ----
        if (m0 + 63 > n0) {
            const int mb = m0 + 4 * half;
#pragma unroll
            for (int r = 0; r < 16; ++r) {
                int mg = mb + (r & 3) + 8 * (r >> 2);
                if (mg > ng)      s0[r] = -1e30f;
                if (mg + 32 > ng) s1[r] = -1e30f;
            }
        }
        // ---- online softmax over m ----
        float mx = s0[0];
#pragma unroll
        for (int r = 1; r < 16; ++r) mx = fmaxf(mx, s0[r]);
#pragma unroll
        for (int r = 0; r < 16; ++r) mx = fmaxf(mx, s1[r]);
        mx = fmaxf(mx, __shfl_xor(mx, 32));
        float nm = fmaxf(m_run, mx);
        float scale = __expf(m_run - nm);
        m_run = nm;
        float rs = 0.f;
#pragma unroll
        for (int r = 0; r < 16; ++r) { s0[r] = __expf(s0[r] - nm); rs += s0[r]; }
#pragma unroll
        for (int r = 0; r < 16; ++r) { s1[r] = __expf(s1[r] - nm); rs += s1[r]; }
        rs += __shfl_xor(rs, 32);
        l_run = l_run * scale + rs;
        acc0 *= scale;
        acc1 *= scale;

        // ---- P -> bf16 B-frags in-register, PV accumulate ----
#pragma unroll
        for (int kc = 0; kc < 4; ++kc) {
            float p0, p1, p2, p3, p4, p5, p6, p7;
            if (kc == 0)      { p0=s0[0]; p1=s0[1]; p2=s0[2]; p3=s0[3]; p4=s0[4]; p5=s0[5]; p6=s0[6]; p7=s0[7]; }
            else if (kc == 1) { p0=s0[8]; p1=s0[9]; p2=s0[10]; p3=s0[11]; p4=s0[12]; p5=s0[13]; p6=s0[14]; p7=s0[15]; }
            else if (kc == 2) { p0=s1[0]; p1=s1[1]; p2=s1[2]; p3=s1[3]; p4=s1[4]; p5=s1[5]; p6=s1[6]; p7=s1[7]; }
            else              { p0=s1[8]; p1=s1[9]; p2=s1[10]; p3=s1[11]; p4=s1[12]; p5=s1[13]; p6=s1[14]; p7=s1[15]; }
            unsigned a0 = cvtpk(p0, p1), a1 = cvtpk(p2, p3);
            unsigned a2 = cvtpk(p4, p5), a3 = cvtpk(p6, p7);
            unsigned t0 = __shfl_xor(a0, 32), t1 = __shfl_xor(a1, 32);
            unsigned t2 = __shfl_xor(a2, 32), t3 = __shfl_xor(a3, 32);
            union { unsigned u[4]; bf16x8 v; } pb;
            pb.u[0] = half ? t2 : a0;
            pb.u[1] = half ? t3 : a1;
            pb.u[2] = half ? a2 : t0;
            pb.u[3] = half ? a3 : t1;
            bf16x8 va0 = *(const bf16x8*)&Vfp[(((size_t)j * 4 + kc) * 2 + 0) * 512 + lane * 8];
            bf16x8 va1 = *(const bf16x8*)&Vfp[(((size_t)j * 4 + kc) * 2 + 1) * 512 + lane * 8];
            acc0 = MFMA32(va0, pb.v, acc0, 0, 0, 0);
            acc1 = MFMA32(va1, pb.v, acc1, 0, 0, 0);
        }
    }

    // ---- merge the two partial states of each slice ----
    if (par) {
#pragma unroll
        for (int r = 0; r < 16; ++r) {
            mbuf[sl][lane][r]      = acc0[r];
            mbuf[sl][lane][16 + r] = acc1[r];
        }
        mbuf[sl][lane][32] = m_run;
        mbuf[sl][lane][33] = l_run;
    }
    __syncthreads();
    if (!par) {
        float mB = mbuf[sl][lane][32], lB = mbuf[sl][lane][33];
        float nm = fmaxf(m_run, mB);
        float sA = __expf(m_run - nm), sB = __expf(mB - nm);
        float l = l_run * sA + lB * sB;
#pragma unroll
        for (int r = 0; r < 16; ++r) {
            acc0[r] = acc0[r] * sA + mbuf[sl][lane][r] * sB;
            acc1[r] = acc1[r] * sA + mbuf[sl][lane][16 + r] * sB;
        }
        // ---- epilogue: normalize, transpose via LDS, coalesced store ----
        float inv = 1.0f / l;
#pragma unroll
        for (int r = 0; r < 16; ++r) {
            int d0 = (r & 3) + 8 * (r >> 2) + 4 * half;
            ot[sl][col][d0]      = __float2bfloat16(acc0[r] * inv);
            ot[sl][col][32 + d0] = __float2bfloat16(acc1[r] * inv);
        }
        const int b = bh >> 4, h = bh & 15;
#pragma unroll
        for (int tt = 0; tt < 16; ++tt) {
            int rrow = tt * 2 + half;
            unsigned v = *(const unsigned*)&ot[sl][rrow][col * 2];
            *(unsigned*)&sa[((size_t)(b * 2048 + n0 + rrow)) * 1024 + h * 64 + col * 2] = v;
        }
    }
}

// ---------------- output projection (128x128) ----------------
__global__ __launch_bounds__(256) void gemm_proj(const __hip_bfloat16* __restrict__ Ag,
                                                 const __hip_bfloat16* __restrict__ Btg,
                                                 const float* __restrict__ bias,
                                                 float* __restrict__ out) {
    __shared__ __hip_bfloat16 As[128 * 64];
    __shared__ __hip_bfloat16 Bs[128 * 64];
    const int t = threadIdx.x;
    const int lane = t & 63, wid = t >> 6;
    const int wm = wid >> 1, wn = wid & 1;
    const int row0 = blockIdx.y * 128, col0 = blockIdx.x * 128;
    const int lr = lane & 15, lg = lane >> 4;
    const int srow = wid * 8 + (lane >> 3);
    const int scol = (lane & 7) * 8;

    f32x4 acc[4][4] = {};
    for (int k0 = 0; k0 < 1024; k0 += 64) {
#pragma unroll
        for (int c = 0; c < 4; ++c) {
            gld16(&Ag[(size_t)(row0 + c * 32 + srow) * 1024 + k0 + scol],
                  &As[(c * 32 + wid * 8) * 64]);
            gld16(&Btg[(size_t)(col0 + c * 32 + srow) * 1024 + k0 + scol],
                  &Bs[(c * 32 + wid * 8) * 64]);
        }
        __syncthreads();
#pragma unroll
        for (int kk = 0; kk < 64; kk += 32) {
            bf16x8 af[4], bfr[4];
#pragma unroll
            for (int i = 0; i < 4; ++i)
                af[i] = *(const bf16x8*)&As[(wm * 64 + i * 16 + lr) * 64 + kk + 8 * lg];
#pragma unroll
            for (int j = 0; j < 4; ++j)
                bfr[j] = *(const bf16x8*)&Bs[(wn * 64 + j * 16 + lr) * 64 + kk + 8 * lg];
#pragma unroll
            for (int i = 0; i < 4; ++i)
#pragma unroll
                for (int j = 0; j < 4; ++j)
                    acc[i][j] = MFMA_BF16(af[i], bfr[j], acc[i][j], 0, 0, 0);
        }
        __syncthreads();
    }
#pragma unroll
    for (int i = 0; i < 4; ++i)
#pragma unroll
        for (int j = 0; j < 4; ++j)
#pragma unroll
            for (int r = 0; r < 4; ++r) {
                int rg = row0 + wm * 64 + i * 16 + lg * 4 + r;
                int cg = col0 + wn * 64 + j * 16 + lr;
                out[(size_t)rg * 1024 + cg] = acc[i][j][r] + bias[cg];
            }
}

// ---------------- launch ----------------
extern "C" void kernel_launch(void* const* d_in, const int* in_sizes, int n_in,
                              void* d_out, int out_size, void* d_ws, size_t ws_size,
                              hipStream_t stream) {
    const float* x     = (const float*)d_in[0];  // [2,2048,1024]
    const float* Wkqv  = (const float*)d_in[1];  // [16,1024,192]
    const float* bkqv  = (const float*)d_in[2];  // [16,192] -> flat [3072]
    const float* Wproj = (const float*)d_in[3];  // [1024,1024]
    const float* bproj = (const float*)d_in[4];  // [1024]

    char* w = (char*)d_ws;
    // workspace layout (48 MB, with region reuse):
    // [0,8M):   xb, then Kf (repack output)
    // [8M,16M): Wt (first 6M), then Qf
    // [16M,40M): C, then WpT at [16M,18M) + sab at [18M,26M)
    // [40M,48M): Vf
    __hip_bfloat16* xb  = (__hip_bfloat16*)(w + 0);
    __hip_bfloat16* Wt  = (__hip_bfloat16*)(w + 8388608);
    __hip_bfloat16* C   = (__hip_bfloat16*)(w + 16777216);
    __hip_bfloat16* Kf  = (__hip_bfloat16*)(w + 0);
    __hip_bfloat16* Qf  = (__hip_bfloat16*)(w + 8388608);
    __hip_bfloat16* Vf  = (__hip_bfloat16*)(w + 41943040);
    __hip_bfloat16* WpT = (__hip_bfloat16*)(w + 16777216);
    __hip_bfloat16* sab = (__hip_bfloat16*)(w + 18874368);
    if (ws_size < 50331648) return;

    cvt_f32_bf16<<<4096, 256, 0, stream>>>(x, xb);
    transpose_cvt<<<dim3(6, 32, 16), dim3(32, 8), 0, stream>>>(Wkqv, Wt, 1024, 192);
    gemm_qkv<<<dim3(24, 32), 256, 0, stream>>>(xb, Wt, bkqv, C);
    repack_qkv<<<dim3(32, 32), 256, 0, stream>>>(C, Kf, Qf, Vf);
    transpose_cvt<<<dim3(32, 32, 1), dim3(32, 8), 0, stream>>>(Wproj, WpT, 1024, 1024);
    attn_fwd<<<dim3(32, 32), 256, 0, stream>>>(Kf, Qf, Vf, sab);
    gemm_proj<<<dim3(8, 32), 256, 0, stream>>>(sab, WpT, bproj, (float*)d_out);
}

// Round 5
// 131.388 us; speedup vs baseline: 2.5969x; 1.3983x over previous
//
#include <hip/hip_runtime.h>
#include <hip/hip_bf16.h>

// Problem dims (fixed)
// B=2, N=2048, D=1024, H=16, DK=64
// x: [2,2048,1024] f32; Wkqv: [16,1024,192] f32; bkqv: [16,192] f32;
// Wproj: [1024,1024] f32; bproj: [1024] f32; out: [2,2048,1024] f32

typedef __bf16 bf16x8 __attribute__((ext_vector_type(8)));
typedef float f32x4 __attribute__((ext_vector_type(4)));
typedef float f32x16 __attribute__((ext_vector_type(16)));

#define MFMA_BF16 __builtin_amdgcn_mfma_f32_16x16x32_bf16
#define MFMA32 __builtin_amdgcn_mfma_f32_32x32x16_bf16

static __device__ __forceinline__ unsigned cvtpk(float lo, float hi) {
    unsigned r;
    asm("v_cvt_pk_bf16_f32 %0, %1, %2" : "=v"(r) : "v"(lo), "v"(hi));
    return r;
}

// async global -> LDS, 16 B per lane; lds base must be wave-uniform
static __device__ __forceinline__ void gld16(const void* g, void* l) {
    __builtin_amdgcn_global_load_lds(
        (const __attribute__((address_space(1))) unsigned int*)g,
        (__attribute__((address_space(3))) unsigned int*)l, 16, 0, 0);
}

// ---------------- prep kernels ----------------

__global__ __launch_bounds__(256) void cvt_f32_bf16(const float* __restrict__ in,
                                                    __hip_bfloat16* __restrict__ out) {
    int i = (blockIdx.x * 256 + threadIdx.x) * 4;
    float4 v = *(const float4*)&in[i];
    struct alignas(8) bh4 { __hip_bfloat16 a, b, c, d; };
    bh4 r{__float2bfloat16(v.x), __float2bfloat16(v.y),
          __float2bfloat16(v.z), __float2bfloat16(v.w)};
    *(bh4*)&out[i] = r;
}

// in [b][R][C] f32 -> out [b][C][R] bf16 ; 32x32 tiles, block (32,8)
__global__ __launch_bounds__(256) void transpose_cvt(const float* __restrict__ in,
                                                     __hip_bfloat16* __restrict__ out,
                                                     int R, int C) {
    __shared__ float tile[32][33];
    int b = blockIdx.z;
    int r0 = blockIdx.y * 32, c0 = blockIdx.x * 32;
    int tx = threadIdx.x, ty = threadIdx.y;
    const float* ip = in + (size_t)b * R * C;
    __hip_bfloat16* op = out + (size_t)b * R * C;
#pragma unroll
    for (int j = 0; j < 32; j += 8)
        tile[ty + j][tx] = ip[(size_t)(r0 + ty + j) * C + (c0 + tx)];
    __syncthreads();
#pragma unroll
    for (int j = 0; j < 32; j += 8)
        op[(size_t)(c0 + ty + j) * R + (r0 + tx)] = __float2bfloat16(tile[tx][ty + j]);
}

// ---------------- QKV GEMM (128x128, BK=64, global_load_lds) ----
__global__ __launch_bounds__(256) void gemm_qkv(const __hip_bfloat16* __restrict__ Ag,
                                                const __hip_bfloat16* __restrict__ Btg,
                                                const float* __restrict__ bias,
                                                __hip_bfloat16* __restrict__ C) {
    __shared__ __hip_bfloat16 As[128 * 64];
    __shared__ __hip_bfloat16 Bs[128 * 64];
    const int t = threadIdx.x;
    const int lane = t & 63, wid = t >> 6;
    const int wm = wid >> 1, wn = wid & 1;
    const int row0 = blockIdx.y * 128, col0 = blockIdx.x * 128;
    const int lr = lane & 15, lg = lane >> 4;
    const int srow = wid * 8 + (lane >> 3);
    const int scol = (lane & 7) * 8;

    f32x4 acc[4][4] = {};
    for (int k0 = 0; k0 < 1024; k0 += 64) {
#pragma unroll
        for (int c = 0; c < 4; ++c) {
            gld16(&Ag[(size_t)(row0 + c * 32 + srow) * 1024 + k0 + scol],
                  &As[(c * 32 + wid * 8) * 64]);
            gld16(&Btg[(size_t)(col0 + c * 32 + srow) * 1024 + k0 + scol],
                  &Bs[(c * 32 + wid * 8) * 64]);
        }
        __syncthreads();
#pragma unroll
        for (int kk = 0; kk < 64; kk += 32) {
            bf16x8 af[4], bfr[4];
#pragma unroll
            for (int i = 0; i < 4; ++i)
                af[i] = *(const bf16x8*)&As[(wm * 64 + i * 16 + lr) * 64 + kk + 8 * lg];
#pragma unroll
            for (int j = 0; j < 4; ++j)
                bfr[j] = *(const bf16x8*)&Bs[(wn * 64 + j * 16 + lr) * 64 + kk + 8 * lg];
#pragma unroll
            for (int i = 0; i < 4; ++i)
#pragma unroll
                for (int j = 0; j < 4; ++j)
                    acc[i][j] = MFMA_BF16(af[i], bfr[j], acc[i][j], 0, 0, 0);
        }
        __syncthreads();
    }
#pragma unroll
    for (int i = 0; i < 4; ++i)
#pragma unroll
        for (int j = 0; j < 4; ++j)
#pragma unroll
            for (int r = 0; r < 4; ++r) {
                int rg = row0 + wm * 64 + i * 16 + lg * 4 + r;
                int cg = col0 + wn * 64 + j * 16 + lr;
                float v = acc[i][j][r] + bias[cg];
                if (cg % 3 == 0) v *= 0.125f;  // K pre-scale
                C[(size_t)rg * 3072 + cg] = __float2bfloat16(v);
            }
}

// ---------------- repack C -> fragment-major K/Q/V ----------------
__global__ __launch_bounds__(256) void repack_qkv(const __hip_bfloat16* __restrict__ C,
                                                  __hip_bfloat16* __restrict__ Kf,
                                                  __hip_bfloat16* __restrict__ Qf,
                                                  __hip_bfloat16* __restrict__ Vf) {
    __shared__ __hip_bfloat16 tile[64][200];
    const int mt = blockIdx.x, bh = blockIdx.y;
    const int b = bh >> 4, h = bh & 15;
    const __hip_bfloat16* Cp = C + ((size_t)(b * 2048 + mt * 64)) * 3072 + h * 192;
    const int t = threadIdx.x;
#pragma unroll
    for (int r = 0; r < 6; ++r) {
        int idx = t + 256 * r;
        int row = idx / 24, seg = idx % 24;
        *(uint4*)&tile[row][seg * 8] = *(const uint4*)&Cp[(size_t)row * 3072 + seg * 8];
    }
    __syncthreads();
    const size_t qbase = ((size_t)bh * 32 + mt) * 4096;
    const size_t kbase = ((size_t)bh * 64 + mt * 2) * 2048;
    const size_t vbase = ((size_t)bh * 32 + mt) * 4096;
#pragma unroll
    for (int c = 0; c < 2; ++c) {
        int chunk = t + 256 * c;
        int l = chunk & 63, blk = chunk >> 6;
        int hi = l >> 5, lo = l & 31;
        {
            int sub = blk >> 2, dc = blk & 3;
            int row = sub * 32 + lo, dbase = dc * 16 + 8 * hi;
            ushort u[8];
#pragma unroll
            for (int i = 0; i < 8; ++i)
                u[i] = *(const ushort*)&tile[row][(dbase + i) * 3 + 1];
            *(uint4*)&Qf[qbase + (size_t)chunk * 8] = *(const uint4*)u;
        }
        {
            int sub2 = blk >> 2, dc = blk & 3;
            int row = sub2 * 32 + lo, dbase = dc * 16 + 8 * hi;
            ushort u[8];
#pragma unroll
            for (int i = 0; i < 8; ++i)
                u[i] = *(const ushort*)&tile[row][(dbase + i) * 3];
            *(uint4*)&Kf[kbase + (size_t)chunk * 8] = *(const uint4*)u;
        }
        {
            int kc = blk >> 1, accN = blk & 1;
            int col = (accN * 32 + lo) * 3 + 2, rbase = kc * 16 + 8 * hi;
            ushort u[8];
#pragma unroll
            for (int i = 0; i < 8; ++i)
                u[i] = *(const ushort*)&tile[rbase + i][col];
            *(uint4*)&Vf[vbase + (size_t)chunk * 8] = *(const uint4*)u;
        }
    }
}

// ---------------- flash attention (swapped 32x32, 4-way m-split) ----------
// One slice per block, 4 waves = parity 0..3 over m-tiles; wave-0 merges.
// Block id swizzle: each XCD owns 4 bh (3 MB working set -> L2-resident);
// longest slices dispatch first.
__global__ __launch_bounds__(256, 3) void attn_fwd(const __hip_bfloat16* __restrict__ Kf,
                                                   const __hip_bfloat16* __restrict__ Qf,
                                                   const __hip_bfloat16* __restrict__ Vf,
                                                   __hip_bfloat16* __restrict__ sa) {
    __shared__ float mbuf[3][64][35];
    __shared__ __hip_bfloat16 ot[32][66];
    const int id = blockIdx.x;
    const int xcd = id & 7, qq = id >> 3;
    const int bh = xcd * 4 + (qq & 3);
    const int slice = 63 - (qq >> 2);
    const int t = threadIdx.x, lane = t & 63, wid = t >> 6;
    const int col = lane & 31, half = lane >> 5;
    const int par = wid;
    const int n0 = slice * 32;

    const __hip_bfloat16* Kfp = Kf + (size_t)bh * 131072;
    const __hip_bfloat16* Qfp = Qf + (size_t)bh * 131072;
    const __hip_bfloat16* Vfp = Vf + (size_t)bh * 131072;

    // K fragments, loaded once (coalesced)
    bf16x8 kf[4];
#pragma unroll
    for (int dc = 0; dc < 4; ++dc)
        kf[dc] = *(const bf16x8*)&Kfp[((size_t)slice * 4 + dc) * 512 + lane * 8];

    f32x16 acc0 = {}, acc1 = {};
    float m_run = -3.0e29f, l_run = 0.f;
    const int ng = n0 + col;
    const int T = (n0 + 95) >> 6;  // number of 64-wide m tiles for this slice

    // Q prefetch registers
    bf16x8 qa[4], qb[4];
    if (par < T) {
#pragma unroll
        for (int dc = 0; dc < 4; ++dc) {
            qa[dc] = *(const bf16x8*)&Qfp[(((size_t)par * 2 + 0) * 4 + dc) * 512 + lane * 8];
            qb[dc] = *(const bf16x8*)&Qfp[(((size_t)par * 2 + 1) * 4 + dc) * 512 + lane * 8];
        }
    }

    for (int j = par; j < T; j += 4) {
        const int m0 = j << 6;
        // ---- issue V loads for this tile (consumed after softmax) ----
        bf16x8 va[4], vb[4];
#pragma unroll
        for (int kc = 0; kc < 4; ++kc) {
            va[kc] = *(const bf16x8*)&Vfp[(((size_t)j * 4 + kc) * 2 + 0) * 512 + lane * 8];
            vb[kc] = *(const bf16x8*)&Vfp[(((size_t)j * 4 + kc) * 2 + 1) * 512 + lane * 8];
        }
        // ---- S = Q-tile @ K ----
        f32x16 s0 = {}, s1 = {};
        __builtin_amdgcn_s_setprio(1);
#pragma unroll
        for (int dc = 0; dc < 4; ++dc) s0 = MFMA32(qa[dc], kf[dc], s0, 0, 0, 0);
#pragma unroll
        for (int dc = 0; dc < 4; ++dc) s1 = MFMA32(qb[dc], kf[dc], s1, 0, 0, 0);
        __builtin_amdgcn_s_setprio(0);
        // ---- prefetch next Q tile for this wave ----
        if (j + 4 < T) {
#pragma unroll
            for (int dc = 0; dc < 4; ++dc) {
                qa[dc] = *(const bf16x8*)&Qfp[(((size_t)(j + 4) * 2 + 0) * 4 + dc) * 512 + lane * 8];
                qb[dc] = *(const bf16x8*)&Qfp[(((size_t)(j + 4) * 2 + 1) * 4 + dc) * 512 + lane * 8];
            }
        }
        // ---- causal mask (only near-diagonal tiles) ----
        if (m0 + 63 > n0) {
            const int mb = m0 + 4 * half;
#pragma unroll
            for (int r = 0; r < 16; ++r) {
                int mg = mb + (r & 3) + 8 * (r >> 2);
                if (mg > ng)      s0[r] = -1e30f;
                if (mg + 32 > ng) s1[r] = -1e30f;
            }
        }
        // ---- online softmax over m ----
        float mx = s0[0];
#pragma unroll
        for (int r = 1; r < 16; ++r) mx = fmaxf(mx, s0[r]);
#pragma unroll
        for (int r = 0; r < 16; ++r) mx = fmaxf(mx, s1[r]);
        mx = fmaxf(mx, __shfl_xor(mx, 32));
        float nm = fmaxf(m_run, mx);
        float scale = __expf(m_run - nm);
        m_run = nm;
        float rs = 0.f;
#pragma unroll
        for (int r = 0; r < 16; ++r) { s0[r] = __expf(s0[r] - nm); rs += s0[r]; }
#pragma unroll
        for (int r = 0; r < 16; ++r) { s1[r] = __expf(s1[r] - nm); rs += s1[r]; }
        rs += __shfl_xor(rs, 32);
        l_run = l_run * scale + rs;
        acc0 *= scale;
        acc1 *= scale;

        // ---- P -> bf16 B-frags in-register, PV accumulate ----
#pragma unroll
        for (int kc = 0; kc < 4; ++kc) {
            float p0, p1, p2, p3, p4, p5, p6, p7;
            if (kc == 0)      { p0=s0[0]; p1=s0[1]; p2=s0[2]; p3=s0[3]; p4=s0[4]; p5=s0[5]; p6=s0[6]; p7=s0[7]; }
            else if (kc == 1) { p0=s0[8]; p1=s0[9]; p2=s0[10]; p3=s0[11]; p4=s0[12]; p5=s0[13]; p6=s0[14]; p7=s0[15]; }
            else if (kc == 2) { p0=s1[0]; p1=s1[1]; p2=s1[2]; p3=s1[3]; p4=s1[4]; p5=s1[5]; p6=s1[6]; p7=s1[7]; }
            else              { p0=s1[8]; p1=s1[9]; p2=s1[10]; p3=s1[11]; p4=s1[12]; p5=s1[13]; p6=s1[14]; p7=s1[15]; }
            unsigned a0 = cvtpk(p0, p1), a1 = cvtpk(p2, p3);
            unsigned a2 = cvtpk(p4, p5), a3 = cvtpk(p6, p7);
            unsigned t0 = __shfl_xor(a0, 32), t1 = __shfl_xor(a1, 32);
            unsigned t2 = __shfl_xor(a2, 32), t3 = __shfl_xor(a3, 32);
            union { unsigned u[4]; bf16x8 v; } pb;
            pb.u[0] = half ? t2 : a0;
            pb.u[1] = half ? t3 : a1;
            pb.u[2] = half ? a2 : t0;
            pb.u[3] = half ? a3 : t1;
            __builtin_amdgcn_s_setprio(1);
            acc0 = MFMA32(va[kc], pb.v, acc0, 0, 0, 0);
            acc1 = MFMA32(vb[kc], pb.v, acc1, 0, 0, 0);
            __builtin_amdgcn_s_setprio(0);
        }
    }

    // ---- merge the 4 partial states (waves 1-3 -> LDS, wave 0 combines) ----
    if (wid) {
#pragma unroll
        for (int r = 0; r < 16; ++r) {
            mbuf[wid - 1][lane][r]      = acc0[r];
            mbuf[wid - 1][lane][16 + r] = acc1[r];
        }
        mbuf[wid - 1][lane][32] = m_run;
        mbuf[wid - 1][lane][33] = l_run;
    }
    __syncthreads();
    if (!wid) {
#pragma unroll
        for (int w = 0; w < 3; ++w) {
            float mB = mbuf[w][lane][32], lB = mbuf[w][lane][33];
            float nm = fmaxf(m_run, mB);
            float sA = __expf(m_run - nm), sB = __expf(mB - nm);
            m_run = nm;
            l_run = l_run * sA + lB * sB;
#pragma unroll
            for (int r = 0; r < 16; ++r) {
                acc0[r] = acc0[r] * sA + mbuf[w][lane][r] * sB;
                acc1[r] = acc1[r] * sA + mbuf[w][lane][16 + r] * sB;
            }
        }
        // ---- epilogue: normalize, transpose via LDS, coalesced store ----
        float inv = 1.0f / l_run;
#pragma unroll
        for (int r = 0; r < 16; ++r) {
            int d0 = (r & 3) + 8 * (r >> 2) + 4 * half;
            ot[col][d0]      = __float2bfloat16(acc0[r] * inv);
            ot[col][32 + d0] = __float2bfloat16(acc1[r] * inv);
        }
        const int b = bh >> 4, h = bh & 15;
#pragma unroll
        for (int tt = 0; tt < 16; ++tt) {
            int rrow = tt * 2 + half;
            unsigned v = *(const unsigned*)&ot[rrow][col * 2];
            *(unsigned*)&sa[((size_t)(b * 2048 + n0 + rrow)) * 1024 + h * 64 + col * 2] = v;
        }
    }
}

// ---------------- output projection (128x128) ----------------
__global__ __launch_bounds__(256) void gemm_proj(const __hip_bfloat16* __restrict__ Ag,
                                                 const __hip_bfloat16* __restrict__ Btg,
                                                 const float* __restrict__ bias,
                                                 float* __restrict__ out) {
    __shared__ __hip_bfloat16 As[128 * 64];
    __shared__ __hip_bfloat16 Bs[128 * 64];
    const int t = threadIdx.x;
    const int lane = t & 63, wid = t >> 6;
    const int wm = wid >> 1, wn = wid & 1;
    const int row0 = blockIdx.y * 128, col0 = blockIdx.x * 128;
    const int lr = lane & 15, lg = lane >> 4;
    const int srow = wid * 8 + (lane >> 3);
    const int scol = (lane & 7) * 8;

    f32x4 acc[4][4] = {};
    for (int k0 = 0; k0 < 1024; k0 += 64) {
#pragma unroll
        for (int c = 0; c < 4; ++c) {
            gld16(&Ag[(size_t)(row0 + c * 32 + srow) * 1024 + k0 + scol],
                  &As[(c * 32 + wid * 8) * 64]);
            gld16(&Btg[(size_t)(col0 + c * 32 + srow) * 1024 + k0 + scol],
                  &Bs[(c * 32 + wid * 8) * 64]);
        }
        __syncthreads();
#pragma unroll
        for (int kk = 0; kk < 64; kk += 32) {
            bf16x8 af[4], bfr[4];
#pragma unroll
            for (int i = 0; i < 4; ++i)
                af[i] = *(const bf16x8*)&As[(wm * 64 + i * 16 + lr) * 64 + kk + 8 * lg];
#pragma unroll
            for (int j = 0; j < 4; ++j)
                bfr[j] = *(const bf16x8*)&Bs[(wn * 64 + j * 16 + lr) * 64 + kk + 8 * lg];
#pragma unroll
            for (int i = 0; i < 4; ++i)
#pragma unroll
                for (int j = 0; j < 4; ++j)
                    acc[i][j] = MFMA_BF16(af[i], bfr[j], acc[i][j], 0, 0, 0);
        }
        __syncthreads();
    }
#pragma unroll
    for (int i = 0; i < 4; ++i)
#pragma unroll
        for (int j = 0; j < 4; ++j)
#pragma unroll
            for (int r = 0; r < 4; ++r) {
                int rg = row0 + wm * 64 + i * 16 + lg * 4 + r;
                int cg = col0 + wn * 64 + j * 16 + lr;
                out[(size_t)rg * 1024 + cg] = acc[i][j][r] + bias[cg];
            }
}

// ---------------- launch ----------------
extern "C" void kernel_launch(void* const* d_in, const int* in_sizes, int n_in,
                              void* d_out, int out_size, void* d_ws, size_t ws_size,
                              hipStream_t stream) {
    const float* x     = (const float*)d_in[0];  // [2,2048,1024]
    const float* Wkqv  = (const float*)d_in[1];  // [16,1024,192]
    const float* bkqv  = (const float*)d_in[2];  // [16,192] -> flat [3072]
    const float* Wproj = (const float*)d_in[3];  // [1024,1024]
    const float* bproj = (const float*)d_in[4];  // [1024]

    char* w = (char*)d_ws;
    // workspace layout (48 MB, with region reuse):
    // [0,8M):   xb, then Kf (repack output)
    // [8M,16M): Wt (first 6M), then Qf
    // [16M,40M): C, then WpT at [16M,18M) + sab at [18M,26M)
    // [40M,48M): Vf
    __hip_bfloat16* xb  = (__hip_bfloat16*)(w + 0);
    __hip_bfloat16* Wt  = (__hip_bfloat16*)(w + 8388608);
    __hip_bfloat16* C   = (__hip_bfloat16*)(w + 16777216);
    __hip_bfloat16* Kf  = (__hip_bfloat16*)(w + 0);
    __hip_bfloat16* Qf  = (__hip_bfloat16*)(w + 8388608);
    __hip_bfloat16* Vf  = (__hip_bfloat16*)(w + 41943040);
    __hip_bfloat16* WpT = (__hip_bfloat16*)(w + 16777216);
    __hip_bfloat16* sab = (__hip_bfloat16*)(w + 18874368);
    if (ws_size < 50331648) return;

    cvt_f32_bf16<<<4096, 256, 0, stream>>>(x, xb);
    transpose_cvt<<<dim3(6, 32, 16), dim3(32, 8), 0, stream>>>(Wkqv, Wt, 1024, 192);
    gemm_qkv<<<dim3(24, 32), 256, 0, stream>>>(xb, Wt, bkqv, C);
    repack_qkv<<<dim3(32, 32), 256, 0, stream>>>(C, Kf, Qf, Vf);
    transpose_cvt<<<dim3(32, 32, 1), dim3(32, 8), 0, stream>>>(Wproj, WpT, 1024, 1024);
    attn_fwd<<<2048, 256, 0, stream>>>(Kf, Qf, Vf, sab);
    gemm_proj<<<dim3(8, 32), 256, 0, stream>>>(sab, WpT, bproj, (float*)d_out);
}

// Round 6
// 115.447 us; speedup vs baseline: 2.9555x; 1.1381x over previous
//
#include <hip/hip_runtime.h>
#include <hip/hip_bf16.h>

// Problem dims (fixed)
// B=2, N=2048, D=1024, H=16, DK=64
// x: [2,2048,1024] f32; Wkqv: [16,1024,192] f32; bkqv: [16,192] f32;
// Wproj: [1024,1024] f32; bproj: [1024] f32; out: [2,2048,1024] f32

typedef __bf16 bf16x8 __attribute__((ext_vector_type(8)));
typedef float f32x4 __attribute__((ext_vector_type(4)));
typedef float f32x16 __attribute__((ext_vector_type(16)));

#define MFMA_BF16 __builtin_amdgcn_mfma_f32_16x16x32_bf16
#define MFMA32 __builtin_amdgcn_mfma_f32_32x32x16_bf16

static __device__ __forceinline__ unsigned cvtpk(float lo, float hi) {
    unsigned r;
    asm("v_cvt_pk_bf16_f32 %0, %1, %2" : "=v"(r) : "v"(lo), "v"(hi));
    return r;
}

// async global -> LDS, 16 B per lane; lds base must be wave-uniform
static __device__ __forceinline__ void gld16(const void* g, void* l) {
    __builtin_amdgcn_global_load_lds(
        (const __attribute__((address_space(1))) unsigned int*)g,
        (__attribute__((address_space(3))) unsigned int*)l, 16, 0, 0);
}

// ---------------- prep kernels ----------------

__global__ __launch_bounds__(256) void cvt_f32_bf16(const float* __restrict__ in,
                                                    __hip_bfloat16* __restrict__ out) {
    int i = (blockIdx.x * 256 + threadIdx.x) * 4;
    float4 v = *(const float4*)&in[i];
    struct alignas(8) bh4 { __hip_bfloat16 a, b, c, d; };
    bh4 r{__float2bfloat16(v.x), __float2bfloat16(v.y),
          __float2bfloat16(v.z), __float2bfloat16(v.w)};
    *(bh4*)&out[i] = r;
}

// in [b][R][C] f32 -> out [b][C][R] bf16 ; 32x32 tiles, block (32,8)
__global__ __launch_bounds__(256) void transpose_cvt(const float* __restrict__ in,
                                                     __hip_bfloat16* __restrict__ out,
                                                     int R, int C) {
    __shared__ float tile[32][33];
    int b = blockIdx.z;
    int r0 = blockIdx.y * 32, c0 = blockIdx.x * 32;
    int tx = threadIdx.x, ty = threadIdx.y;
    const float* ip = in + (size_t)b * R * C;
    __hip_bfloat16* op = out + (size_t)b * R * C;
#pragma unroll
    for (int j = 0; j < 32; j += 8)
        tile[ty + j][tx] = ip[(size_t)(r0 + ty + j) * C + (c0 + tx)];
    __syncthreads();
#pragma unroll
    for (int j = 0; j < 32; j += 8)
        op[(size_t)(c0 + ty + j) * R + (r0 + tx)] = __float2bfloat16(tile[tx][ty + j]);
}

// ---------------- QKV GEMM (256x256, BK=64, 8 waves, counted-vmcnt dbuf) ----
// C[4096][3072] = A[4096][1024] @ Bt[3072][1024]^T + bias (cols cg%3==0 also
// pre-scaled by 1/8 = the K score scale). Plain coalesced bf16 output.
// LDS: 2 x (256x64 A + 256x64 B) = 128 KiB, XOR-swizzled slots (slot ^= row&7)
// on BOTH the global source (pre-swizzle, linear gld_lds dest) and the ds_read.
__global__ __launch_bounds__(512) void gemm_qkv(const __hip_bfloat16* __restrict__ Ag,
                                                const __hip_bfloat16* __restrict__ Btg,
                                                const float* __restrict__ bias,
                                                __hip_bfloat16* __restrict__ C) {
    __shared__ __hip_bfloat16 As[2][256 * 64];
    __shared__ __hip_bfloat16 Bs[2][256 * 64];
    const int t = threadIdx.x;
    const int lane = t & 63, wid = t >> 6;  // 8 waves
    const int wm = wid >> 2, wn = wid & 3;  // 2 x 4
    const int row0 = blockIdx.y * 256, col0 = blockIdx.x * 256;
    const int lr = lane & 15, lg = lane >> 4;
    // staging: per wave-instruction 64 lanes x 16B = 8 rows x 8 slots (1 KiB)
    const int g_r = lane >> 3;                     // row within 8-row group
    const int g_s8 = ((lane & 7) ^ g_r) * 8;       // inverse-swizzled src slot
    // ds_read swizzled slot bases (elements)
    const int sw0 = ((lg) ^ (lr & 7)) * 8;         // kk=0..31
    const int sw1 = ((4 + lg) ^ (lr & 7)) * 8;     // kk=32..63

#define STAGE_QKV(buf, kt)                                                            \
    do {                                                                              \
        const int k0_ = (kt) * 64;                                                    \
        _Pragma("unroll") for (int r_ = 0; r_ < 4; ++r_) {                            \
            const int grp_ = r_ * 8 + wid;                                            \
            gld16(&Ag[(size_t)(row0 + grp_ * 8 + g_r) * 1024 + k0_ + g_s8],           \
                  &As[buf][grp_ * 512]);                                              \
            gld16(&Btg[(size_t)(col0 + grp_ * 8 + g_r) * 1024 + k0_ + g_s8],          \
                  &Bs[buf][grp_ * 512]);                                              \
        }                                                                             \
    } while (0)

    f32x4 acc[8][4] = {};

    // prologue: stage tiles 0,1 into bufs 0,1; wait tile0 only
    STAGE_QKV(0, 0);
    STAGE_QKV(1, 1);
    asm volatile("s_waitcnt vmcnt(8)" ::: "memory");
    __builtin_amdgcn_sched_barrier(0);
    __builtin_amdgcn_s_barrier();
    __builtin_amdgcn_sched_barrier(0);

    int cur = 0;
    for (int kt = 0; kt < 16; ++kt) {
        const __hip_bfloat16* Ab = &As[cur][0];
        const __hip_bfloat16* Bb = &Bs[cur][0];
        bf16x8 af[8], bf[4];
        // ---- kk = 0..31 ----
#pragma unroll
        for (int j = 0; j < 4; ++j)
            bf[j] = *(const bf16x8*)&Bb[(wn * 64 + j * 16 + lr) * 64 + sw0];
#pragma unroll
        for (int i = 0; i < 8; ++i)
            af[i] = *(const bf16x8*)&Ab[(wm * 128 + i * 16 + lr) * 64 + sw0];
        __builtin_amdgcn_s_setprio(1);
#pragma unroll
        for (int i = 0; i < 8; ++i)
#pragma unroll
            for (int j = 0; j < 4; ++j)
                acc[i][j] = MFMA_BF16(af[i], bf[j], acc[i][j], 0, 0, 0);
        __builtin_amdgcn_s_setprio(0);
        // ---- kk = 32..63 (reads issued, then all-reads barrier) ----
#pragma unroll
        for (int j = 0; j < 4; ++j)
            bf[j] = *(const bf16x8*)&Bb[(wn * 64 + j * 16 + lr) * 64 + sw1];
#pragma unroll
        for (int i = 0; i < 8; ++i)
            af[i] = *(const bf16x8*)&Ab[(wm * 128 + i * 16 + lr) * 64 + sw1];
        asm volatile("s_waitcnt lgkmcnt(0)" ::: "memory");
        __builtin_amdgcn_sched_barrier(0);
        __builtin_amdgcn_s_barrier();
        __builtin_amdgcn_sched_barrier(0);
        // buffer cur is free -> stage tile kt+2 into it (loads span the barrier)
        if (kt + 2 < 16) STAGE_QKV(cur, kt + 2);
        __builtin_amdgcn_s_setprio(1);
#pragma unroll
        for (int i = 0; i < 8; ++i)
#pragma unroll
            for (int j = 0; j < 4; ++j)
                acc[i][j] = MFMA_BF16(af[i], bf[j], acc[i][j], 0, 0, 0);
        __builtin_amdgcn_s_setprio(0);
        // wait for tile kt+1 (8 oldest loads); keep kt+2's 8 in flight
        if (kt <= 13) {
            asm volatile("s_waitcnt vmcnt(8)" ::: "memory");
        } else {
            asm volatile("s_waitcnt vmcnt(0)" ::: "memory");
        }
        __builtin_amdgcn_sched_barrier(0);
        __builtin_amdgcn_s_barrier();
        __builtin_amdgcn_sched_barrier(0);
        cur ^= 1;
    }
#undef STAGE_QKV

#pragma unroll
    for (int i = 0; i < 8; ++i)
#pragma unroll
        for (int j = 0; j < 4; ++j)
#pragma unroll
            for (int r = 0; r < 4; ++r) {
                int rg = row0 + wm * 128 + i * 16 + lg * 4 + r;
                int cg = col0 + wn * 64 + j * 16 + lr;
                float v = acc[i][j][r] + bias[cg];
                if (cg % 3 == 0) v *= 0.125f;  // K pre-scale
                C[(size_t)rg * 3072 + cg] = __float2bfloat16(v);
            }
}

// ---------------- repack C -> fragment-major K/Q/V ----------------
__global__ __launch_bounds__(256) void repack_qkv(const __hip_bfloat16* __restrict__ C,
                                                  __hip_bfloat16* __restrict__ Kf,
                                                  __hip_bfloat16* __restrict__ Qf,
                                                  __hip_bfloat16* __restrict__ Vf) {
    __shared__ __hip_bfloat16 tile[64][200];
    const int mt = blockIdx.x, bh = blockIdx.y;
    const int b = bh >> 4, h = bh & 15;
    const __hip_bfloat16* Cp = C + ((size_t)(b * 2048 + mt * 64)) * 3072 + h * 192;
    const int t = threadIdx.x;
#pragma unroll
    for (int r = 0; r < 6; ++r) {
        int idx = t + 256 * r;
        int row = idx / 24, seg = idx % 24;
        *(uint4*)&tile[row][seg * 8] = *(const uint4*)&Cp[(size_t)row * 3072 + seg * 8];
    }
    __syncthreads();
    const size_t qbase = ((size_t)bh * 32 + mt) * 4096;
    const size_t kbase = ((size_t)bh * 64 + mt * 2) * 2048;
    const size_t vbase = ((size_t)bh * 32 + mt) * 4096;
#pragma unroll
    for (int c = 0; c < 2; ++c) {
        int chunk = t + 256 * c;
        int l = chunk & 63, blk = chunk >> 6;
        int hi = l >> 5, lo = l & 31;
        {
            int sub = blk >> 2, dc = blk & 3;
            int row = sub * 32 + lo, dbase = dc * 16 + 8 * hi;
            ushort u[8];
#pragma unroll
            for (int i = 0; i < 8; ++i)
                u[i] = *(const ushort*)&tile[row][(dbase + i) * 3 + 1];
            *(uint4*)&Qf[qbase + (size_t)chunk * 8] = *(const uint4*)u;
        }
        {
            int sub2 = blk >> 2, dc = blk & 3;
            int row = sub2 * 32 + lo, dbase = dc * 16 + 8 * hi;
            ushort u[8];
#pragma unroll
            for (int i = 0; i < 8; ++i)
                u[i] = *(const ushort*)&tile[row][(dbase + i) * 3];
            *(uint4*)&Kf[kbase + (size_t)chunk * 8] = *(const uint4*)u;
        }
        {
            int kc = blk >> 1, accN = blk & 1;
            int col = (accN * 32 + lo) * 3 + 2, rbase = kc * 16 + 8 * hi;
            ushort u[8];
#pragma unroll
            for (int i = 0; i < 8; ++i)
                u[i] = *(const ushort*)&tile[rbase + i][col];
            *(uint4*)&Vf[vbase + (size_t)chunk * 8] = *(const uint4*)u;
        }
    }
}

// ---------------- flash attention (swapped 32x32, 4-way m-split) ----------
__global__ __launch_bounds__(256, 3) void attn_fwd(const __hip_bfloat16* __restrict__ Kf,
                                                   const __hip_bfloat16* __restrict__ Qf,
                                                   const __hip_bfloat16* __restrict__ Vf,
                                                   __hip_bfloat16* __restrict__ sa) {
    __shared__ float mbuf[3][64][35];
    __shared__ __hip_bfloat16 ot[32][66];
    const int id = blockIdx.x;
    const int xcd = id & 7, qq = id >> 3;
    const int bh = xcd * 4 + (qq & 3);
    const int slice = 63 - (qq >> 2);
    const int t = threadIdx.x, lane = t & 63, wid = t >> 6;
    const int col = lane & 31, half = lane >> 5;
    const int par = wid;
    const int n0 = slice * 32;

    const __hip_bfloat16* Kfp = Kf + (size_t)bh * 131072;
    const __hip_bfloat16* Qfp = Qf + (size_t)bh * 131072;
    const __hip_bfloat16* Vfp = Vf + (size_t)bh * 131072;

    bf16x8 kf[4];
#pragma unroll
    for (int dc = 0; dc < 4; ++dc)
        kf[dc] = *(const bf16x8*)&Kfp[((size_t)slice * 4 + dc) * 512 + lane * 8];

    f32x16 acc0 = {}, acc1 = {};
    float m_run = -3.0e29f, l_run = 0.f;
    const int ng = n0 + col;
    const int T = (n0 + 95) >> 6;

    bf16x8 qa[4], qb[4];
    if (par < T) {
#pragma unroll
        for (int dc = 0; dc < 4; ++dc) {
            qa[dc] = *(const bf16x8*)&Qfp[(((size_t)par * 2 + 0) * 4 + dc) * 512 + lane * 8];
            qb[dc] = *(const bf16x8*)&Qfp[(((size_t)par * 2 + 1) * 4 + dc) * 512 + lane * 8];
        }
    }

    for (int j = par; j < T; j += 4) {
        const int m0 = j << 6;
        bf16x8 va[4], vb[4];
#pragma unroll
        for (int kc = 0; kc < 4; ++kc) {
            va[kc] = *(const bf16x8*)&Vfp[(((size_t)j * 4 + kc) * 2 + 0) * 512 + lane * 8];
            vb[kc] = *(const bf16x8*)&Vfp[(((size_t)j * 4 + kc) * 2 + 1) * 512 + lane * 8];
        }
        f32x16 s0 = {}, s1 = {};
        __builtin_amdgcn_s_setprio(1);
#pragma unroll
        for (int dc = 0; dc < 4; ++dc) s0 = MFMA32(qa[dc], kf[dc], s0, 0, 0, 0);
#pragma unroll
        for (int dc = 0; dc < 4; ++dc) s1 = MFMA32(qb[dc], kf[dc], s1, 0, 0, 0);
        __builtin_amdgcn_s_setprio(0);
        if (j + 4 < T) {
#pragma unroll
            for (int dc = 0; dc < 4; ++dc) {
                qa[dc] = *(const bf16x8*)&Qfp[(((size_t)(j + 4) * 2 + 0) * 4 + dc) * 512 + lane * 8];
                qb[dc] = *(const bf16x8*)&Qfp[(((size_t)(j + 4) * 2 + 1) * 4 + dc) * 512 + lane * 8];
            }
        }
        if (m0 + 63 > n0) {
            const int mb = m0 + 4 * half;
#pragma unroll
            for (int r = 0; r < 16; ++r) {
                int mg = mb + (r & 3) + 8 * (r >> 2);
                if (mg > ng)      s0[r] = -1e30f;
                if (mg + 32 > ng) s1[r] = -1e30f;
            }
        }
        float mx = s0[0];
#pragma unroll
        for (int r = 1; r < 16; ++r) mx = fmaxf(mx, s0[r]);
#pragma unroll
        for (int r = 0; r < 16; ++r) mx = fmaxf(mx, s1[r]);
        mx = fmaxf(mx, __shfl_xor(mx, 32));
        float nm = fmaxf(m_run, mx);
        float scale = __expf(m_run - nm);
        m_run = nm;
        float rs = 0.f;
#pragma unroll
        for (int r = 0; r < 16; ++r) { s0[r] = __expf(s0[r] - nm); rs += s0[r]; }
#pragma unroll
        for (int r = 0; r < 16; ++r) { s1[r] = __expf(s1[r] - nm); rs += s1[r]; }
        rs += __shfl_xor(rs, 32);
        l_run = l_run * scale + rs;
        acc0 *= scale;
        acc1 *= scale;

#pragma unroll
        for (int kc = 0; kc < 4; ++kc) {
            float p0, p1, p2, p3, p4, p5, p6, p7;
            if (kc == 0)      { p0=s0[0]; p1=s0[1]; p2=s0[2]; p3=s0[3]; p4=s0[4]; p5=s0[5]; p6=s0[6]; p7=s0[7]; }
            else if (kc == 1) { p0=s0[8]; p1=s0[9]; p2=s0[10]; p3=s0[11]; p4=s0[12]; p5=s0[13]; p6=s0[14]; p7=s0[15]; }
            else if (kc == 2) { p0=s1[0]; p1=s1[1]; p2=s1[2]; p3=s1[3]; p4=s1[4]; p5=s1[5]; p6=s1[6]; p7=s1[7]; }
            else              { p0=s1[8]; p1=s1[9]; p2=s1[10]; p3=s1[11]; p4=s1[12]; p5=s1[13]; p6=s1[14]; p7=s1[15]; }
            unsigned a0 = cvtpk(p0, p1), a1 = cvtpk(p2, p3);
            unsigned a2 = cvtpk(p4, p5), a3 = cvtpk(p6, p7);
            unsigned t0 = __shfl_xor(a0, 32), t1 = __shfl_xor(a1, 32);
            unsigned t2 = __shfl_xor(a2, 32), t3 = __shfl_xor(a3, 32);
            union { unsigned u[4]; bf16x8 v; } pb;
            pb.u[0] = half ? t2 : a0;
            pb.u[1] = half ? t3 : a1;
            pb.u[2] = half ? a2 : t0;
            pb.u[3] = half ? a3 : t1;
            __builtin_amdgcn_s_setprio(1);
            acc0 = MFMA32(va[kc], pb.v, acc0, 0, 0, 0);
            acc1 = MFMA32(vb[kc], pb.v, acc1, 0, 0, 0);
            __builtin_amdgcn_s_setprio(0);
        }
    }

    if (wid) {
#pragma unroll
        for (int r = 0; r < 16; ++r) {
            mbuf[wid - 1][lane][r]      = acc0[r];
            mbuf[wid - 1][lane][16 + r] = acc1[r];
        }
        mbuf[wid - 1][lane][32] = m_run;
        mbuf[wid - 1][lane][33] = l_run;
    }
    __syncthreads();
    if (!wid) {
#pragma unroll
        for (int w = 0; w < 3; ++w) {
            float mB = mbuf[w][lane][32], lB = mbuf[w][lane][33];
            float nm = fmaxf(m_run, mB);
            float sA = __expf(m_run - nm), sB = __expf(mB - nm);
            m_run = nm;
            l_run = l_run * sA + lB * sB;
#pragma unroll
            for (int r = 0; r < 16; ++r) {
                acc0[r] = acc0[r] * sA + mbuf[w][lane][r] * sB;
                acc1[r] = acc1[r] * sA + mbuf[w][lane][16 + r] * sB;
            }
        }
        float inv = 1.0f / l_run;
#pragma unroll
        for (int r = 0; r < 16; ++r) {
            int d0 = (r & 3) + 8 * (r >> 2) + 4 * half;
            ot[col][d0]      = __float2bfloat16(acc0[r] * inv);
            ot[col][32 + d0] = __float2bfloat16(acc1[r] * inv);
        }
        const int b = bh >> 4, h = bh & 15;
#pragma unroll
        for (int tt = 0; tt < 16; ++tt) {
            int rrow = tt * 2 + half;
            unsigned v = *(const unsigned*)&ot[rrow][col * 2];
            *(unsigned*)&sa[((size_t)(b * 2048 + n0 + rrow)) * 1024 + h * 64 + col * 2] = v;
        }
    }
}

// ---------------- output projection (128x128) ----------------
__global__ __launch_bounds__(256) void gemm_proj(const __hip_bfloat16* __restrict__ Ag,
                                                 const __hip_bfloat16* __restrict__ Btg,
                                                 const float* __restrict__ bias,
                                                 float* __restrict__ out) {
    __shared__ __hip_bfloat16 As[128 * 64];
    __shared__ __hip_bfloat16 Bs[128 * 64];
    const int t = threadIdx.x;
    const int lane = t & 63, wid = t >> 6;
    const int wm = wid >> 1, wn = wid & 1;
    const int row0 = blockIdx.y * 128, col0 = blockIdx.x * 128;
    const int lr = lane & 15, lg = lane >> 4;
    const int srow = wid * 8 + (lane >> 3);
    const int scol = (lane & 7) * 8;

    f32x4 acc[4][4] = {};
    for (int k0 = 0; k0 < 1024; k0 += 64) {
#pragma unroll
        for (int c = 0; c < 4; ++c) {
            gld16(&Ag[(size_t)(row0 + c * 32 + srow) * 1024 + k0 + scol],
                  &As[(c * 32 + wid * 8) * 64]);
            gld16(&Btg[(size_t)(col0 + c * 32 + srow) * 1024 + k0 + scol],
                  &Bs[(c * 32 + wid * 8) * 64]);
        }
        __syncthreads();
#pragma unroll
        for (int kk = 0; kk < 64; kk += 32) {
            bf16x8 af[4], bfr[4];
#pragma unroll
            for (int i = 0; i < 4; ++i)
                af[i] = *(const bf16x8*)&As[(wm * 64 + i * 16 + lr) * 64 + kk + 8 * lg];
#pragma unroll
            for (int j = 0; j < 4; ++j)
                bfr[j] = *(const bf16x8*)&Bs[(wn * 64 + j * 16 + lr) * 64 + kk + 8 * lg];
#pragma unroll
            for (int i = 0; i < 4; ++i)
#pragma unroll
                for (int j = 0; j < 4; ++j)
                    acc[i][j] = MFMA_BF16(af[i], bfr[j], acc[i][j], 0, 0, 0);
        }
        __syncthreads();
    }
#pragma unroll
    for (int i = 0; i < 4; ++i)
#pragma unroll
        for (int j = 0; j < 4; ++j)
#pragma unroll
            for (int r = 0; r < 4; ++r) {
                int rg = row0 + wm * 64 + i * 16 + lg * 4 + r;
                int cg = col0 + wn * 64 + j * 16 + lr;
                out[(size_t)rg * 1024 + cg] = acc[i][j][r] + bias[cg];
            }
}

// ---------------- launch ----------------
extern "C" void kernel_launch(void* const* d_in, const int* in_sizes, int n_in,
                              void* d_out, int out_size, void* d_ws, size_t ws_size,
                              hipStream_t stream) {
    const float* x     = (const float*)d_in[0];  // [2,2048,1024]
    const float* Wkqv  = (const float*)d_in[1];  // [16,1024,192]
    const float* bkqv  = (const float*)d_in[2];  // [16,192] -> flat [3072]
    const float* Wproj = (const float*)d_in[3];  // [1024,1024]
    const float* bproj = (const float*)d_in[4];  // [1024]

    char* w = (char*)d_ws;
    // workspace layout (48 MB, with region reuse):
    // [0,8M):   xb, then Kf (repack output)
    // [8M,16M): Wt (first 6M), then Qf
    // [16M,40M): C, then WpT at [16M,18M) + sab at [18M,26M)
    // [40M,48M): Vf
    __hip_bfloat16* xb  = (__hip_bfloat16*)(w + 0);
    __hip_bfloat16* Wt  = (__hip_bfloat16*)(w + 8388608);
    __hip_bfloat16* C   = (__hip_bfloat16*)(w + 16777216);
    __hip_bfloat16* Kf  = (__hip_bfloat16*)(w + 0);
    __hip_bfloat16* Qf  = (__hip_bfloat16*)(w + 8388608);
    __hip_bfloat16* Vf  = (__hip_bfloat16*)(w + 41943040);
    __hip_bfloat16* WpT = (__hip_bfloat16*)(w + 16777216);
    __hip_bfloat16* sab = (__hip_bfloat16*)(w + 18874368);
    if (ws_size < 50331648) return;

    cvt_f32_bf16<<<4096, 256, 0, stream>>>(x, xb);
    transpose_cvt<<<dim3(6, 32, 16), dim3(32, 8), 0, stream>>>(Wkqv, Wt, 1024, 192);
    gemm_qkv<<<dim3(12, 16), 512, 0, stream>>>(xb, Wt, bkqv, C);
    repack_qkv<<<dim3(32, 32), 256, 0, stream>>>(C, Kf, Qf, Vf);
    transpose_cvt<<<dim3(32, 32, 1), dim3(32, 8), 0, stream>>>(Wproj, WpT, 1024, 1024);
    attn_fwd<<<2048, 256, 0, stream>>>(Kf, Qf, Vf, sab);
    gemm_proj<<<dim3(8, 32), 256, 0, stream>>>(sab, WpT, bproj, (float*)d_out);
}

// Round 7
// 99.392 us; speedup vs baseline: 3.4329x; 1.1615x over previous
//
#include <hip/hip_runtime.h>
#include <hip/hip_bf16.h>

// Problem dims (fixed)
// B=2, N=2048, D=1024, H=16, DK=64
// x: [2,2048,1024] f32; Wkqv: [16,1024,192] f32; bkqv: [16,192] f32;
// Wproj: [1024,1024] f32; bproj: [1024] f32; out: [2,2048,1024] f32

typedef __bf16 bf16x8 __attribute__((ext_vector_type(8)));
typedef float f32x4 __attribute__((ext_vector_type(4)));
typedef float f32x16 __attribute__((ext_vector_type(16)));

#define MFMA_BF16 __builtin_amdgcn_mfma_f32_16x16x32_bf16
#define MFMA32 __builtin_amdgcn_mfma_f32_32x32x16_bf16

static __device__ __forceinline__ unsigned cvtpk(float lo, float hi) {
    unsigned r;
    asm("v_cvt_pk_bf16_f32 %0, %1, %2" : "=v"(r) : "v"(lo), "v"(hi));
    return r;
}

// async global -> LDS, 16 B per lane; lds base must be wave-uniform
static __device__ __forceinline__ void gld16(const void* g, void* l) {
    __builtin_amdgcn_global_load_lds(
        (const __attribute__((address_space(1))) unsigned int*)g,
        (__attribute__((address_space(3))) unsigned int*)l, 16, 0, 0);
}

// ---------------- prep kernels ----------------

__global__ __launch_bounds__(256) void cvt_f32_bf16(const float* __restrict__ in,
                                                    __hip_bfloat16* __restrict__ out) {
    int i = (blockIdx.x * 256 + threadIdx.x) * 4;
    float4 v = *(const float4*)&in[i];
    struct alignas(8) bh4 { __hip_bfloat16 a, b, c, d; };
    bh4 r{__float2bfloat16(v.x), __float2bfloat16(v.y),
          __float2bfloat16(v.z), __float2bfloat16(v.w)};
    *(bh4*)&out[i] = r;
}

// in [b][R][C] f32 -> out [b][C][R] bf16 ; 32x32 tiles, block (32,8)
__global__ __launch_bounds__(256) void transpose_cvt(const float* __restrict__ in,
                                                     __hip_bfloat16* __restrict__ out,
                                                     int R, int C) {
    __shared__ float tile[32][33];
    int b = blockIdx.z;
    int r0 = blockIdx.y * 32, c0 = blockIdx.x * 32;
    int tx = threadIdx.x, ty = threadIdx.y;
    const float* ip = in + (size_t)b * R * C;
    __hip_bfloat16* op = out + (size_t)b * R * C;
#pragma unroll
    for (int j = 0; j < 32; j += 8)
        tile[ty + j][tx] = ip[(size_t)(r0 + ty + j) * C + (c0 + tx)];
    __syncthreads();
#pragma unroll
    for (int j = 0; j < 32; j += 8)
        op[(size_t)(c0 + ty + j) * R + (r0 + tx)] = __float2bfloat16(tile[tx][ty + j]);
}

// ---------------- QKV GEMM (256x192 tile = one head, fused repack) --------
// Per block: rows row0..row0+256 of x (bn), cols = head h's 192 outputs.
// Counted-vmcnt double-buffered K-loop (BK=64, 16 tiles), 8 waves (2x4),
// per-wave 128x48 output. Epilogue: acc(+bias, K*1/8) -> LDS [256][204] ->
// fragment-major Kf/Qf/Vf direct (repack fused; C never materialized).
__global__ __launch_bounds__(512) void gemm_qkv(const __hip_bfloat16* __restrict__ Ag,
                                                const __hip_bfloat16* __restrict__ Btg,
                                                const float* __restrict__ bias,
                                                __hip_bfloat16* __restrict__ Kf,
                                                __hip_bfloat16* __restrict__ Qf,
                                                __hip_bfloat16* __restrict__ Vf) {
    __shared__ __hip_bfloat16 smem[57344];  // dbuf: A 2x16384 | B 2x12288; reused by epilogue
    const int t = threadIdx.x;
    const int lane = t & 63, wid = t >> 6;  // 8 waves
    const int wm = wid >> 2, wn = wid & 3;  // 2 x 4
    const int h = blockIdx.x;               // head = N-tile (192 cols)
    const int row0 = blockIdx.y * 256;
    const int col0 = h * 192;
    const int lr = lane & 15, lg = lane >> 4;
    const int g_r = lane >> 3;                   // row within 8-row staging group
    const int g_s8 = ((lane & 7) ^ g_r) * 8;     // inverse-swizzled global slot
    const int sw0 = ((lg) ^ (lr & 7)) * 8;       // swizzled ds_read slot, kk=0..31
    const int sw1 = ((4 + lg) ^ (lr & 7)) * 8;   // kk=32..63

#define STAGE_QKV(buf, kt)                                                            \
    do {                                                                              \
        const int k0_ = (kt) * 64;                                                    \
        __hip_bfloat16* Ad_ = smem + (buf) * 16384;                                   \
        __hip_bfloat16* Bd_ = smem + 32768 + (buf) * 12288;                           \
        _Pragma("unroll") for (int r_ = 0; r_ < 4; ++r_) {                            \
            const int grp_ = r_ * 8 + wid;                                            \
            gld16(&Ag[(size_t)(row0 + grp_ * 8 + g_r) * 1024 + k0_ + g_s8],           \
                  Ad_ + grp_ * 512);                                                  \
        }                                                                             \
        _Pragma("unroll") for (int r_ = 0; r_ < 3; ++r_) {                            \
            const int grp_ = r_ * 8 + wid;                                            \
            gld16(&Btg[(size_t)(col0 + grp_ * 8 + g_r) * 1024 + k0_ + g_s8],          \
                  Bd_ + grp_ * 512);                                                  \
        }                                                                             \
    } while (0)

    f32x4 acc[8][3] = {};

    // prologue: stage tiles 0,1; wait for tile 0 only (7 loads/stage)
    STAGE_QKV(0, 0);
    STAGE_QKV(1, 1);
    asm volatile("s_waitcnt vmcnt(7)" ::: "memory");
    __builtin_amdgcn_sched_barrier(0);
    __builtin_amdgcn_s_barrier();
    __builtin_amdgcn_sched_barrier(0);

    int cur = 0;
    for (int kt = 0; kt < 16; ++kt) {
        const __hip_bfloat16* Ab = smem + cur * 16384;
        const __hip_bfloat16* Bb = smem + 32768 + cur * 12288;
        bf16x8 af[8], bf[3];
        // ---- kk = 0..31 ----
#pragma unroll
        for (int j = 0; j < 3; ++j)
            bf[j] = *(const bf16x8*)&Bb[(wn * 48 + j * 16 + lr) * 64 + sw0];
#pragma unroll
        for (int i = 0; i < 8; ++i)
            af[i] = *(const bf16x8*)&Ab[(wm * 128 + i * 16 + lr) * 64 + sw0];
        __builtin_amdgcn_s_setprio(1);
#pragma unroll
        for (int i = 0; i < 8; ++i)
#pragma unroll
            for (int j = 0; j < 3; ++j)
                acc[i][j] = MFMA_BF16(af[i], bf[j], acc[i][j], 0, 0, 0);
        __builtin_amdgcn_s_setprio(0);
        // ---- kk = 32..63 ----
#pragma unroll
        for (int j = 0; j < 3; ++j)
            bf[j] = *(const bf16x8*)&Bb[(wn * 48 + j * 16 + lr) * 64 + sw1];
#pragma unroll
        for (int i = 0; i < 8; ++i)
            af[i] = *(const bf16x8*)&Ab[(wm * 128 + i * 16 + lr) * 64 + sw1];
        asm volatile("s_waitcnt lgkmcnt(0)" ::: "memory");
        __builtin_amdgcn_sched_barrier(0);
        __builtin_amdgcn_s_barrier();
        __builtin_amdgcn_sched_barrier(0);
        // buffer cur free -> stage tile kt+2 into it (loads span barriers)
        if (kt + 2 < 16) STAGE_QKV(cur, kt + 2);
        __builtin_amdgcn_s_setprio(1);
#pragma unroll
        for (int i = 0; i < 8; ++i)
#pragma unroll
            for (int j = 0; j < 3; ++j)
                acc[i][j] = MFMA_BF16(af[i], bf[j], acc[i][j], 0, 0, 0);
        __builtin_amdgcn_s_setprio(0);
        if (kt <= 13) {
            asm volatile("s_waitcnt vmcnt(7)" ::: "memory");  // tile kt+1 ready, kt+2 in flight
        } else {
            asm volatile("s_waitcnt vmcnt(0)" ::: "memory");
        }
        __builtin_amdgcn_sched_barrier(0);
        __builtin_amdgcn_s_barrier();
        __builtin_amdgcn_sched_barrier(0);
        cur ^= 1;
    }
#undef STAGE_QKV

    // ---- fused epilogue: acc -> LDS [256][204] (bias + K-scale applied) ----
    const int b = row0 >> 11, n_base = row0 & 2047, bh = b * 16 + h;
    __hip_bfloat16 (*tile)[204] = (__hip_bfloat16 (*)[204])smem;
#pragma unroll
    for (int i = 0; i < 8; ++i)
#pragma unroll
        for (int j = 0; j < 3; ++j)
#pragma unroll
            for (int r = 0; r < 4; ++r) {
                int trow = wm * 128 + i * 16 + lg * 4 + r;
                int tcol = wn * 48 + j * 16 + lr;
                float v = acc[i][j][r] + bias[col0 + tcol];
                if (tcol % 3 == 0) v *= 0.125f;  // K pre-scale
                tile[trow][tcol] = __float2bfloat16(v);
            }
    __syncthreads();
    // ---- fragment-major writes (identical mapping to validated repack) ----
#pragma unroll
    for (int k = 0; k < 4; ++k) {
        const int c = t + 512 * k;
        const int l = c & 63, lo = l & 31, hi = l >> 5;
        // K: chunks [so(8)][dc(4)][l(64)] ; elem = tile[so*32+lo][3*(dc*16+8*hi+i)]
        {
            const int dc = (c >> 6) & 3, so = c >> 8;
            ushort u[8];
#pragma unroll
            for (int i = 0; i < 8; ++i)
                u[i] = *(const ushort*)&tile[so * 32 + lo][3 * (dc * 16 + 8 * hi + i)];
            *(uint4*)&Kf[(((size_t)bh * 64 + (n_base >> 5) + so) * 4 + dc) * 512 + l * 8] =
                *(const uint4*)u;
        }
        // Q: chunks [mt_off(4)][sub(2)][dc(4)][l] ; elem = tile[mt_off*64+sub*32+lo][3*d+1]
        {
            const int dc = (c >> 6) & 3, sub = (c >> 8) & 1, mt_off = c >> 9;
            ushort u[8];
#pragma unroll
            for (int i = 0; i < 8; ++i)
                u[i] = *(const ushort*)&tile[mt_off * 64 + sub * 32 + lo]
                                           [3 * (dc * 16 + 8 * hi + i) + 1];
            *(uint4*)&Qf[((((size_t)bh * 32 + (n_base >> 6) + mt_off) * 2 + sub) * 4 + dc) * 512 +
                         l * 8] = *(const uint4*)u;
        }
        // V: chunks [mt_off(4)][kc(4)][accN(2)][l] ; elem = tile[mt_off*64+kc*16+8*hi+i][3*(accN*32+lo)+2]
        {
            const int accN = (c >> 6) & 1, kc = (c >> 7) & 3, mt_off = c >> 9;
            ushort u[8];
#pragma unroll
            for (int i = 0; i < 8; ++i)
                u[i] = *(const ushort*)&tile[mt_off * 64 + kc * 16 + 8 * hi + i]
                                           [3 * (accN * 32 + lo) + 2];
            *(uint4*)&Vf[((((size_t)bh * 32 + (n_base >> 6) + mt_off) * 4 + kc) * 2 + accN) * 512 +
                         l * 8] = *(const uint4*)u;
        }
    }
}

// ---------------- flash attention (swapped 32x32, 4-way m-split) ----------
__global__ __launch_bounds__(256, 3) void attn_fwd(const __hip_bfloat16* __restrict__ Kf,
                                                   const __hip_bfloat16* __restrict__ Qf,
                                                   const __hip_bfloat16* __restrict__ Vf,
                                                   __hip_bfloat16* __restrict__ sa) {
    __shared__ float mbuf[3][64][35];
    __shared__ __hip_bfloat16 ot[32][66];
    const int id = blockIdx.x;
    const int xcd = id & 7, qq = id >> 3;
    const int bh = xcd * 4 + (qq & 3);
    const int slice = 63 - (qq >> 2);
    const int t = threadIdx.x, lane = t & 63, wid = t >> 6;
    const int col = lane & 31, half = lane >> 5;
    const int par = wid;
    const int n0 = slice * 32;

    const __hip_bfloat16* Kfp = Kf + (size_t)bh * 131072;
    const __hip_bfloat16* Qfp = Qf + (size_t)bh * 131072;
    const __hip_bfloat16* Vfp = Vf + (size_t)bh * 131072;

    bf16x8 kf[4];
#pragma unroll
    for (int dc = 0; dc < 4; ++dc)
        kf[dc] = *(const bf16x8*)&Kfp[((size_t)slice * 4 + dc) * 512 + lane * 8];

    f32x16 acc0 = {}, acc1 = {};
    float m_run = -3.0e29f, l_run = 0.f;
    const int ng = n0 + col;
    const int T = (n0 + 95) >> 6;

    bf16x8 qa[4], qb[4];
    if (par < T) {
#pragma unroll
        for (int dc = 0; dc < 4; ++dc) {
            qa[dc] = *(const bf16x8*)&Qfp[(((size_t)par * 2 + 0) * 4 + dc) * 512 + lane * 8];
            qb[dc] = *(const bf16x8*)&Qfp[(((size_t)par * 2 + 1) * 4 + dc) * 512 + lane * 8];
        }
    }

    for (int j = par; j < T; j += 4) {
        const int m0 = j << 6;
        bf16x8 va[4], vb[4];
#pragma unroll
        for (int kc = 0; kc < 4; ++kc) {
            va[kc] = *(const bf16x8*)&Vfp[(((size_t)j * 4 + kc) * 2 + 0) * 512 + lane * 8];
            vb[kc] = *(const bf16x8*)&Vfp[(((size_t)j * 4 + kc) * 2 + 1) * 512 + lane * 8];
        }
        f32x16 s0 = {}, s1 = {};
        __builtin_amdgcn_s_setprio(1);
#pragma unroll
        for (int dc = 0; dc < 4; ++dc) s0 = MFMA32(qa[dc], kf[dc], s0, 0, 0, 0);
#pragma unroll
        for (int dc = 0; dc < 4; ++dc) s1 = MFMA32(qb[dc], kf[dc], s1, 0, 0, 0);
        __builtin_amdgcn_s_setprio(0);
        if (j + 4 < T) {
#pragma unroll
            for (int dc = 0; dc < 4; ++dc) {
                qa[dc] = *(const bf16x8*)&Qfp[(((size_t)(j + 4) * 2 + 0) * 4 + dc) * 512 + lane * 8];
                qb[dc] = *(const bf16x8*)&Qfp[(((size_t)(j + 4) * 2 + 1) * 4 + dc) * 512 + lane * 8];
            }
        }
        if (m0 + 63 > n0) {
            const int mb = m0 + 4 * half;
#pragma unroll
            for (int r = 0; r < 16; ++r) {
                int mg = mb + (r & 3) + 8 * (r >> 2);
                if (mg > ng)      s0[r] = -1e30f;
                if (mg + 32 > ng) s1[r] = -1e30f;
            }
        }
        float mx = s0[0];
#pragma unroll
        for (int r = 1; r < 16; ++r) mx = fmaxf(mx, s0[r]);
#pragma unroll
        for (int r = 0; r < 16; ++r) mx = fmaxf(mx, s1[r]);
        mx = fmaxf(mx, __shfl_xor(mx, 32));
        float nm = fmaxf(m_run, mx);
        float scale = __expf(m_run - nm);
        m_run = nm;
        float rs = 0.f;
#pragma unroll
        for (int r = 0; r < 16; ++r) { s0[r] = __expf(s0[r] - nm); rs += s0[r]; }
#pragma unroll
        for (int r = 0; r < 16; ++r) { s1[r] = __expf(s1[r] - nm); rs += s1[r]; }
        rs += __shfl_xor(rs, 32);
        l_run = l_run * scale + rs;
        acc0 *= scale;
        acc1 *= scale;

#pragma unroll
        for (int kc = 0; kc < 4; ++kc) {
            float p0, p1, p2, p3, p4, p5, p6, p7;
            if (kc == 0)      { p0=s0[0]; p1=s0[1]; p2=s0[2]; p3=s0[3]; p4=s0[4]; p5=s0[5]; p6=s0[6]; p7=s0[7]; }
            else if (kc == 1) { p0=s0[8]; p1=s0[9]; p2=s0[10]; p3=s0[11]; p4=s0[12]; p5=s0[13]; p6=s0[14]; p7=s0[15]; }
            else if (kc == 2) { p0=s1[0]; p1=s1[1]; p2=s1[2]; p3=s1[3]; p4=s1[4]; p5=s1[5]; p6=s1[6]; p7=s1[7]; }
            else              { p0=s1[8]; p1=s1[9]; p2=s1[10]; p3=s1[11]; p4=s1[12]; p5=s1[13]; p6=s1[14]; p7=s1[15]; }
            unsigned a0 = cvtpk(p0, p1), a1 = cvtpk(p2, p3);
            unsigned a2 = cvtpk(p4, p5), a3 = cvtpk(p6, p7);
            unsigned t0 = __shfl_xor(a0, 32), t1 = __shfl_xor(a1, 32);
            unsigned t2 = __shfl_xor(a2, 32), t3 = __shfl_xor(a3, 32);
            union { unsigned u[4]; bf16x8 v; } pb;
            pb.u[0] = half ? t2 : a0;
            pb.u[1] = half ? t3 : a1;
            pb.u[2] = half ? a2 : t0;
            pb.u[3] = half ? a3 : t1;
            __builtin_amdgcn_s_setprio(1);
            acc0 = MFMA32(va[kc], pb.v, acc0, 0, 0, 0);
            acc1 = MFMA32(vb[kc], pb.v, acc1, 0, 0, 0);
            __builtin_amdgcn_s_setprio(0);
        }
    }

    if (wid) {
#pragma unroll
        for (int r = 0; r < 16; ++r) {
            mbuf[wid - 1][lane][r]      = acc0[r];
            mbuf[wid - 1][lane][16 + r] = acc1[r];
        }
        mbuf[wid - 1][lane][32] = m_run;
        mbuf[wid - 1][lane][33] = l_run;
    }
    __syncthreads();
    if (!wid) {
#pragma unroll
        for (int w = 0; w < 3; ++w) {
            float mB = mbuf[w][lane][32], lB = mbuf[w][lane][33];
            float nm = fmaxf(m_run, mB);
            float sA = __expf(m_run - nm), sB = __expf(mB - nm);
            m_run = nm;
            l_run = l_run * sA + lB * sB;
#pragma unroll
            for (int r = 0; r < 16; ++r) {
                acc0[r] = acc0[r] * sA + mbuf[w][lane][r] * sB;
                acc1[r] = acc1[r] * sA + mbuf[w][lane][16 + r] * sB;
            }
        }
        float inv = 1.0f / l_run;
#pragma unroll
        for (int r = 0; r < 16; ++r) {
            int d0 = (r & 3) + 8 * (r >> 2) + 4 * half;
            ot[col][d0]      = __float2bfloat16(acc0[r] * inv);
            ot[col][32 + d0] = __float2bfloat16(acc1[r] * inv);
        }
        const int b = bh >> 4, h = bh & 15;
#pragma unroll
        for (int tt = 0; tt < 16; ++tt) {
            int rrow = tt * 2 + half;
            unsigned v = *(const unsigned*)&ot[rrow][col * 2];
            *(unsigned*)&sa[((size_t)(b * 2048 + n0 + rrow)) * 1024 + h * 64 + col * 2] = v;
        }
    }
}

// ---------------- output projection (128x128, counted-vmcnt dbuf) --------
__global__ __launch_bounds__(256) void gemm_proj(const __hip_bfloat16* __restrict__ Ag,
                                                 const __hip_bfloat16* __restrict__ Btg,
                                                 const float* __restrict__ bias,
                                                 float* __restrict__ out) {
    __shared__ __hip_bfloat16 smem[32768];  // dbuf: A 2x8192 | B 2x8192
    const int t = threadIdx.x;
    const int lane = t & 63, wid = t >> 6;  // 4 waves
    const int wm = wid >> 1, wn = wid & 1;  // 2 x 2
    const int row0 = blockIdx.y * 128, col0 = blockIdx.x * 128;
    const int lr = lane & 15, lg = lane >> 4;
    const int g_r = lane >> 3;
    const int g_s8 = ((lane & 7) ^ g_r) * 8;
    const int sw0 = ((lg) ^ (lr & 7)) * 8;
    const int sw1 = ((4 + lg) ^ (lr & 7)) * 8;

#define STAGE_PROJ(buf, kt)                                                           \
    do {                                                                              \
        const int k0_ = (kt) * 64;                                                    \
        __hip_bfloat16* Ad_ = smem + (buf) * 8192;                                    \
        __hip_bfloat16* Bd_ = smem + 16384 + (buf) * 8192;                            \
        _Pragma("unroll") for (int r_ = 0; r_ < 4; ++r_) {                            \
            const int grp_ = r_ * 4 + wid;                                            \
            gld16(&Ag[(size_t)(row0 + grp_ * 8 + g_r) * 1024 + k0_ + g_s8],           \
                  Ad_ + grp_ * 512);                                                  \
            gld16(&Btg[(size_t)(col0 + grp_ * 8 + g_r) * 1024 + k0_ + g_s8],          \
                  Bd_ + grp_ * 512);                                                  \
        }                                                                             \
    } while (0)

    f32x4 acc[4][4] = {};

    STAGE_PROJ(0, 0);
    STAGE_PROJ(1, 1);
    asm volatile("s_waitcnt vmcnt(8)" ::: "memory");
    __builtin_amdgcn_sched_barrier(0);
    __builtin_amdgcn_s_barrier();
    __builtin_amdgcn_sched_barrier(0);

    int cur = 0;
    for (int kt = 0; kt < 16; ++kt) {
        const __hip_bfloat16* Ab = smem + cur * 8192;
        const __hip_bfloat16* Bb = smem + 16384 + cur * 8192;
        bf16x8 af[4], bf[4];
#pragma unroll
        for (int j = 0; j < 4; ++j)
            bf[j] = *(const bf16x8*)&Bb[(wn * 64 + j * 16 + lr) * 64 + sw0];
#pragma unroll
        for (int i = 0; i < 4; ++i)
            af[i] = *(const bf16x8*)&Ab[(wm * 64 + i * 16 + lr) * 64 + sw0];
        __builtin_amdgcn_s_setprio(1);
#pragma unroll
        for (int i = 0; i < 4; ++i)
#pragma unroll
            for (int j = 0; j < 4; ++j)
                acc[i][j] = MFMA_BF16(af[i], bf[j], acc[i][j], 0, 0, 0);
        __builtin_amdgcn_s_setprio(0);
#pragma unroll
        for (int j = 0; j < 4; ++j)
            bf[j] = *(const bf16x8*)&Bb[(wn * 64 + j * 16 + lr) * 64 + sw1];
#pragma unroll
        for (int i = 0; i < 4; ++i)
            af[i] = *(const bf16x8*)&Ab[(wm * 64 + i * 16 + lr) * 64 + sw1];
        asm volatile("s_waitcnt lgkmcnt(0)" ::: "memory");
        __builtin_amdgcn_sched_barrier(0);
        __builtin_amdgcn_s_barrier();
        __builtin_amdgcn_sched_barrier(0);
        if (kt + 2 < 16) STAGE_PROJ(cur, kt + 2);
        __builtin_amdgcn_s_setprio(1);
#pragma unroll
        for (int i = 0; i < 4; ++i)
#pragma unroll
            for (int j = 0; j < 4; ++j)
                acc[i][j] = MFMA_BF16(af[i], bf[j], acc[i][j], 0, 0, 0);
        __builtin_amdgcn_s_setprio(0);
        if (kt <= 13) {
            asm volatile("s_waitcnt vmcnt(8)" ::: "memory");
        } else {
            asm volatile("s_waitcnt vmcnt(0)" ::: "memory");
        }
        __builtin_amdgcn_sched_barrier(0);
        __builtin_amdgcn_s_barrier();
        __builtin_amdgcn_sched_barrier(0);
        cur ^= 1;
    }
#undef STAGE_PROJ

#pragma unroll
    for (int i = 0; i < 4; ++i)
#pragma unroll
        for (int j = 0; j < 4; ++j)
#pragma unroll
            for (int r = 0; r < 4; ++r) {
                int rg = row0 + wm * 64 + i * 16 + lg * 4 + r;
                int cg = col0 + wn * 64 + j * 16 + lr;
                out[(size_t)rg * 1024 + cg] = acc[i][j][r] + bias[cg];
            }
}

// ---------------- launch ----------------
extern "C" void kernel_launch(void* const* d_in, const int* in_sizes, int n_in,
                              void* d_out, int out_size, void* d_ws, size_t ws_size,
                              hipStream_t stream) {
    const float* x     = (const float*)d_in[0];  // [2,2048,1024]
    const float* Wkqv  = (const float*)d_in[1];  // [16,1024,192]
    const float* bkqv  = (const float*)d_in[2];  // [16,192] -> flat [3072]
    const float* Wproj = (const float*)d_in[3];  // [1024,1024]
    const float* bproj = (const float*)d_in[4];  // [1024]

    char* w = (char*)d_ws;
    // workspace layout (42 MB):
    // [0,8M):    xb (dead after gemm_qkv), then sab (attn output)
    // [8M,14M):  Wt
    // [16M,24M): Kf   [24M,32M): Qf   [32M,40M): Vf
    // [40M,42M): WpT
    __hip_bfloat16* xb  = (__hip_bfloat16*)(w + 0);
    __hip_bfloat16* sab = (__hip_bfloat16*)(w + 0);
    __hip_bfloat16* Wt  = (__hip_bfloat16*)(w + 8388608);
    __hip_bfloat16* Kf  = (__hip_bfloat16*)(w + 16777216);
    __hip_bfloat16* Qf  = (__hip_bfloat16*)(w + 25165824);
    __hip_bfloat16* Vf  = (__hip_bfloat16*)(w + 33554432);
    __hip_bfloat16* WpT = (__hip_bfloat16*)(w + 41943040);
    if (ws_size < 50331648) return;

    cvt_f32_bf16<<<4096, 256, 0, stream>>>(x, xb);
    transpose_cvt<<<dim3(6, 32, 16), dim3(32, 8), 0, stream>>>(Wkqv, Wt, 1024, 192);
    gemm_qkv<<<dim3(16, 16), 512, 0, stream>>>(xb, Wt, bkqv, Kf, Qf, Vf);
    transpose_cvt<<<dim3(32, 32, 1), dim3(32, 8), 0, stream>>>(Wproj, WpT, 1024, 1024);
    attn_fwd<<<2048, 256, 0, stream>>>(Kf, Qf, Vf, sab);
    gemm_proj<<<dim3(8, 32), 256, 0, stream>>>(sab, WpT, bproj, (float*)d_out);
}